// Round 8
// baseline (464.206 us; speedup 1.0000x reference)
//
#include <hip/hip_runtime.h>
#include <cmath>

constexpr int S    = 95;
constexpr int B    = 2;
constexpr int S3   = S * S * S;          // 857375
constexpr int S1   = 47;
constexpr int S13  = S1 * S1 * S1;       // 103823
constexpr int NPTS = 40000;
constexpr int C0   = 8;
constexpr int C1   = 16;
constexpr float EPS = 1e-4f;
constexpr double SSCALE     = 1048576.0;   // 2^20 fixed-point scale for stats
constexpr double INV_SSCALE = 1.0 / 1048576.0;
constexpr int STP = 16;                    // u64 stride per stat slot (one 128B line)

// order-preserving float<->uint encoding (uint compare == float compare)
__device__ __forceinline__ unsigned encf(float f) {
    unsigned b = __float_as_uint(f);
    return (b & 0x80000000u) ? ~b : (b | 0x80000000u);
}
__device__ __forceinline__ float decf(unsigned e) {
    unsigned b = (e & 0x80000000u) ? (e ^ 0x80000000u) : ~e;
    return __uint_as_float(b);
}

// ---------------- deterministic stats accumulation, lane-q mapping ------------
template <int COUT, int SPLIT, int NW>
__device__ __forceinline__ void stats_accum(const float* acc, bool valid,
                                            float* ls, unsigned long long* stat_out) {
    constexpr int CT = COUT / SPLIT;
    float s0[CT], s1[CT];
#pragma unroll
    for (int j = 0; j < CT; ++j) { float v = valid ? acc[j] : 0.f; s0[j] = v; s1[j] = v * v; }
#pragma unroll
    for (int off = SPLIT; off < 64; off <<= 1) {
#pragma unroll
        for (int j = 0; j < CT; ++j) {
            s0[j] += __shfl_xor(s0[j], off, 64);
            s1[j] += __shfl_xor(s1[j], off, 64);
        }
    }
    int tid = threadIdx.x, lane = tid & 63, wv = tid >> 6;
    if (lane < SPLIT) {
#pragma unroll
        for (int j = 0; j < CT; ++j) {
            ls[wv * 2 * COUT + lane * CT + j]        = s0[j];
            ls[wv * 2 * COUT + COUT + lane * CT + j] = s1[j];
        }
    }
    __syncthreads();
    if (tid < 2 * COUT) {
        float t = 0.f;
#pragma unroll
        for (int w = 0; w < NW; ++w) t += ls[w * 2 * COUT + tid];
        long long q = llrint((double)t * SSCALE);
        atomicAdd(&stat_out[(size_t)tid * STP], (unsigned long long)q);
    }
}

// ---------------- deterministic stats accumulation, wave-q mapping ------------
template <int COUT, int SPLIT, int NW>
__device__ __forceinline__ void stats_accum_w(const float* acc, bool valid, int gw0,
                                              float* ls, unsigned long long* stat_out) {
    constexpr int CT = COUT / SPLIT;
    float s0[CT], s1[CT];
#pragma unroll
    for (int j = 0; j < CT; ++j) { float v = valid ? acc[j] : 0.f; s0[j] = v; s1[j] = v * v; }
#pragma unroll
    for (int off = 1; off < 64; off <<= 1) {
#pragma unroll
        for (int j = 0; j < CT; ++j) {
            s0[j] += __shfl_xor(s0[j], off, 64);
            s1[j] += __shfl_xor(s1[j], off, 64);
        }
    }
    int tid = threadIdx.x, lane = tid & 63, wv = tid >> 6;
    if (lane == 0) {
#pragma unroll
        for (int j = 0; j < CT; ++j) {
            ls[wv * 2 * CT + j]      = s0[j];
            ls[wv * 2 * CT + CT + j] = s1[j];
        }
    }
    __syncthreads();
    if (tid < 2 * COUT) {
        int part = tid / COUT;           // 0 = sum, 1 = sumsq
        int ch   = tid - part * COUT;
        int qc   = ch / CT, jj = ch - qc * CT;
        float t = 0.f;
#pragma unroll
        for (int w = 0; w < NW; ++w)
            if (((gw0 + w) % SPLIT) == qc) t += ls[w * 2 * CT + part * CT + jj];
        long long q = llrint((double)t * SSCALE);
        atomicAdd(&stat_out[(size_t)tid * STP], (unsigned long long)q);
    }
}

// compute per-channel scale/shift from int64 stats into LDS
template <int C>
__device__ __forceinline__ void bn_prologue(const unsigned long long* stat_in,
                                            const float* gamma, const float* beta,
                                            const int* cnt_bn, float* s_sc, float* s_sh) {
    int tid = threadIdx.x;
    if (tid < C) {
        double n   = fmax((double)cnt_bn[0], 1.0);
        double sm  = (double)(long long)stat_in[(size_t)tid * STP] * INV_SSCALE;
        double ssq = (double)(long long)stat_in[(size_t)(C + tid) * STP] * INV_SSCALE;
        double mean = sm / n;
        double var  = ssq / n - mean * mean;
        float sc = gamma[tid] * rsqrtf((float)var + EPS);
        s_sc[tid] = sc;
        s_sh[tid] = fmaf(-(float)mean, sc, beta[tid]);
    }
}

// ---------------- scatter + map0 + list0 (wave-aggregated append) ----------------
__global__ __launch_bounds__(256) void k_scatter(const int* __restrict__ coords,
                                                 const float* __restrict__ feats,
                                                 float* __restrict__ grid, int* __restrict__ map0,
                                                 int* __restrict__ list0, int* __restrict__ cnt0) {
    int i = blockIdx.x * 256 + threadIdx.x;
    bool valid = i < NPTS;
    int v = 0; bool own = false;
    if (valid) {
        int x = coords[i * 4 + 0], y = coords[i * 4 + 1], z = coords[i * 4 + 2], b = coords[i * 4 + 3];
        v = ((b * S + x) * S + y) * S + z;
        atomicAdd(&grid[v], feats[i]);
        own = (atomicCAS(&map0[v], 0, -1) == 0);
    }
    unsigned long long m = __ballot(own);
    int lane = threadIdx.x & 63;
    int base = 0;
    if (lane == 0) { int cw = __popcll(m); if (cw) base = atomicAdd(cnt0, cw); }
    base = __shfl(base, 0, 64);
    if (own) {
        int pos = base + __popcll(m & ((1ull << lane) - 1ull));
        list0[pos] = v;
        map0[v] = pos + 1;
    }
}

// ---------------- conv0: 1 -> 8, SAME, + stats ----------------
__global__ __launch_bounds__(256) void k_conv0s(const float* __restrict__ grid,
                                                const int* __restrict__ list, const int* __restrict__ cnt,
                                                const float* __restrict__ w, float* __restrict__ out,
                                                unsigned long long* __restrict__ stat_out) {
    __shared__ float wl[27 * C0];
    __shared__ float ls[4 * 2 * C0];
    const int tid = threadIdx.x;
    if (tid < 27 * C0) wl[tid] = w[tid];
    __syncthreads();
    int i = blockIdx.x * 256 + tid;
    bool valid = i < cnt[0];
    float acc[C0];
#pragma unroll
    for (int c = 0; c < C0; ++c) acc[c] = 0.f;
    if (valid) {
        int v = list[i];
        int z = v % S; int t = v / S;
        int y = t % S; t /= S;
        int x = t % S; int b = t / S;
        float gg[27];
#pragma unroll
        for (int kx = 0; kx < 3; ++kx) {
            int xx = x + kx - 1;
#pragma unroll
            for (int ky = 0; ky < 3; ++ky) {
                int yy = y + ky - 1;
#pragma unroll
                for (int kz = 0; kz < 3; ++kz) {
                    int zz = z + kz - 1;
                    bool in = (unsigned)xx < (unsigned)S && (unsigned)yy < (unsigned)S && (unsigned)zz < (unsigned)S;
                    gg[(kx * 3 + ky) * 3 + kz] = in ? grid[((b * S + xx) * S + yy) * S + zz] : 0.f;
                }
            }
        }
#pragma unroll
        for (int tap = 0; tap < 27; ++tap) {
            float g = gg[tap];
            if (g != 0.f) {
#pragma unroll
                for (int c = 0; c < C0; ++c) acc[c] = fmaf(g, wl[tap * C0 + c], acc[c]);
            }
        }
    }
    stats_accum<C0, 1, 4>(acc, valid, ls, stat_out);
    if (valid) {
#pragma unroll
        for (int c = 0; c < C0; ++c) out[(size_t)i * C0 + c] = acc[c];
    }
}

// ---------------- bn0: apply BN (from stats) in-place + stats of result --------
__global__ __launch_bounds__(256) void k_bn0(float* __restrict__ xs, const int* __restrict__ cnt,
                                             const unsigned long long* __restrict__ stat_in,
                                             const float* __restrict__ gamma, const float* __restrict__ beta,
                                             unsigned long long* __restrict__ stat_out) {
    __shared__ float ls[4 * 2 * C0];
    __shared__ float s_sc[C0], s_sh[C0];
    bn_prologue<C0>(stat_in, gamma, beta, cnt, s_sc, s_sh);
    __syncthreads();
    int tid = threadIdx.x;
    int i = blockIdx.x * 256 + tid;
    bool valid = i < cnt[0];
    float vals[C0];
#pragma unroll
    for (int c = 0; c < C0; ++c) vals[c] = 0.f;
    if (valid) {
#pragma unroll
        for (int c = 0; c < C0; ++c)
            vals[c] = fmaxf(fmaf(xs[(size_t)i * C0 + c], s_sc[c], s_sh[c]), 0.f);
#pragma unroll
        for (int c = 0; c < C0; ++c) xs[(size_t)i * C0 + c] = vals[c];
    }
    stats_accum<C0, 1, 4>(vals, valid, ls, stat_out);
}

// ---------------- L0 fused conv (lane-q, LDS weights, lane-level tap skip) -----
template <int CIN, int COUT, int SPLIT, int SGOUT, int MODE, int TB>
__global__ __launch_bounds__(TB) void k_conv_f(const float* __restrict__ xs,
                                               const unsigned long long* __restrict__ stat_in,
                                               const float* __restrict__ gamma,
                                               const float* __restrict__ beta,
                                               const int* __restrict__ cnt_bn,
                                               const int* __restrict__ map,
                                               const int* __restrict__ list,
                                               const int* __restrict__ cnt,
                                               const float* __restrict__ w,
                                               const float* __restrict__ res,
                                               float* __restrict__ out,
                                               unsigned long long* __restrict__ stat_out,
                                               unsigned* __restrict__ pooled) {
    constexpr int CT = COUT / SPLIT;
    constexpr int NW = TB / 64;
    __shared__ float wl[27 * CIN * COUT];
    __shared__ float ls[NW * 2 * COUT];
    __shared__ float s_sc[CIN], s_sh[CIN];
    const int tid = threadIdx.x;
    const int n_act = cnt[0];
    bn_prologue<CIN>(stat_in, gamma, beta, cnt_bn, s_sc, s_sh);
    const bool blk_on = (int)(((long)blockIdx.x * TB) / SPLIT) < n_act;
    if (blk_on) {
        for (int idx = tid; idx < 27 * CIN * COUT; idx += TB) wl[idx] = w[idx];
    }
    __syncthreads();

    long gt = (long)blockIdx.x * TB + tid;
    int i = (int)(gt / SPLIT), q = (int)(gt % SPLIT);
    bool valid = i < n_act;

    float acc[CT];
#pragma unroll
    for (int j = 0; j < CT; ++j) acc[j] = 0.f;
    if (valid && res) {
#pragma unroll
        for (int j = 0; j < CT; ++j) acc[j] = res[(size_t)i * COUT + q * CT + j];
    }
    if (valid) {
        int v = list[i];
        int z = v % SGOUT; int t2 = v / SGOUT;
        int y = t2 % SGOUT; t2 /= SGOUT;
        int x = t2 % SGOUT; int b = t2 / SGOUT;
        int mm[27];
#pragma unroll
        for (int kx = 0; kx < 3; ++kx) {
            int xx = x + kx - 1;
#pragma unroll
            for (int ky = 0; ky < 3; ++ky) {
                int yy = y + ky - 1;
#pragma unroll
                for (int kz = 0; kz < 3; ++kz) {
                    int zz = z + kz - 1;
                    bool in = ((unsigned)xx < (unsigned)SGOUT && (unsigned)yy < (unsigned)SGOUT &&
                               (unsigned)zz < (unsigned)SGOUT);
                    mm[(kx * 3 + ky) * 3 + kz] = in ? map[((b * SGOUT + xx) * SGOUT + yy) * SGOUT + zz] : 0;
                }
            }
        }
#pragma unroll
        for (int tap = 0; tap < 27; ++tap) {
            int m = mm[tap];
            if (m > 0) {
                const float* row = &xs[(size_t)(m - 1) * CIN];
                float rv[CIN];
                const float4* r4 = reinterpret_cast<const float4*>(row);
#pragma unroll
                for (int u = 0; u < CIN / 4; ++u) {
                    float4 f = r4[u];
                    rv[4 * u] = f.x; rv[4 * u + 1] = f.y; rv[4 * u + 2] = f.z; rv[4 * u + 3] = f.w;
                }
                const float* wt = &wl[tap * CIN * COUT + q * CT];
#pragma unroll
                for (int ci = 0; ci < CIN; ++ci) {
                    float g = fmaxf(fmaf(rv[ci], s_sc[ci], s_sh[ci]), 0.f);
#pragma unroll
                    for (int j = 0; j < CT; ++j) acc[j] = fmaf(g, wt[ci * COUT + j], acc[j]);
                }
            }
        }
    }
    if (MODE == 1) stats_accum<COUT, SPLIT, NW>(acc, valid, ls, stat_out);
    if (valid) {
#pragma unroll
        for (int j = 0; j < CT; ++j) out[(size_t)i * COUT + q * CT + j] = acc[j];
    }
}

// ---------------- L1 fused conv, wave-q (q=wave%SPLIT), SGPR weights -----------
// MODE: 1 = out + stats, 2 = pool epilogue (no out)
template <int CIN, int COUT, int SPLIT, int MODE, int TB>
__global__ __launch_bounds__(TB) void k_conv_w(const float* __restrict__ xs,
                                               const unsigned long long* __restrict__ stat_in,
                                               const float* __restrict__ gamma,
                                               const float* __restrict__ beta,
                                               const int* __restrict__ cnt_bn,
                                               const int* __restrict__ map,
                                               const int* __restrict__ list,
                                               const int* __restrict__ cnt,
                                               const float* __restrict__ w,
                                               const float* __restrict__ res,
                                               float* __restrict__ out,
                                               unsigned long long* __restrict__ stat_out,
                                               unsigned* __restrict__ pooled) {
    constexpr int CT = COUT / SPLIT;
    constexpr int NW = TB / 64;
    __shared__ float ls[NW * 2 * CT];
    __shared__ float s_sc[CIN], s_sh[CIN];
    __shared__ unsigned sm[B * COUT];
    const int tid  = threadIdx.x;
    const int lane = tid & 63;
    const int gw0  = blockIdx.x * NW;
    const int n_act = cnt[0];

    if (MODE == 2 && tid < B * COUT) sm[tid] = 0u;
    bn_prologue<CIN>(stat_in, gamma, beta, cnt_bn, s_sc, s_sh);
    __syncthreads();

    int gw = __builtin_amdgcn_readfirstlane(gw0 + (tid >> 6));
    int q  = gw % SPLIT;
    int c  = gw / SPLIT;
    int i  = c * 64 + lane;
    bool valid = i < n_act;

    float scr[CIN], shr[CIN];
#pragma unroll
    for (int ci = 0; ci < CIN; ++ci) { scr[ci] = s_sc[ci]; shr[ci] = s_sh[ci]; }

    float acc[CT];
#pragma unroll
    for (int j = 0; j < CT; ++j) acc[j] = 0.f;
    int b = 0;

    if (c * 64 < n_act) {                       // wave-uniform early-out for tail
        if (valid && res) {
#pragma unroll
            for (int j = 0; j < CT; ++j) acc[j] = res[(size_t)i * COUT + q * CT + j];
        }
        int mm[27];
#pragma unroll
        for (int t = 0; t < 27; ++t) mm[t] = 0;
        if (valid) {
            int v = list[i];
            int z = v % S1; int t2 = v / S1;
            int y = t2 % S1; t2 /= S1;
            int x = t2 % S1; b = t2 / S1;
#pragma unroll
            for (int kx = 0; kx < 3; ++kx) {
                int xx = x + kx - 1;
#pragma unroll
                for (int ky = 0; ky < 3; ++ky) {
                    int yy = y + ky - 1;
#pragma unroll
                    for (int kz = 0; kz < 3; ++kz) {
                        int zz = z + kz - 1;
                        bool in = (unsigned)xx < (unsigned)S1 && (unsigned)yy < (unsigned)S1 &&
                                  (unsigned)zz < (unsigned)S1;
                        mm[(kx * 3 + ky) * 3 + kz] = in ? map[((b * S1 + xx) * S1 + yy) * S1 + zz] : 0;
                    }
                }
            }
        }
        const float* wq = w + q * CT;           // wave-uniform base
        for (int tap = 0; tap < 27; ++tap) {
            int m = mm[tap];
            float rv[CIN];
            if (m > 0) {
                const float4* r4 = reinterpret_cast<const float4*>(&xs[(size_t)(m - 1) * CIN]);
#pragma unroll
                for (int u = 0; u < CIN / 4; ++u) {
                    float4 f = r4[u];
                    rv[4 * u] = f.x; rv[4 * u + 1] = f.y; rv[4 * u + 2] = f.z; rv[4 * u + 3] = f.w;
                }
            }
            const float* wt = wq + (size_t)tap * CIN * COUT;   // uniform -> s_load
#pragma unroll
            for (int ci = 0; ci < CIN; ++ci) {
                float g = fmaxf(fmaf(rv[ci], scr[ci], shr[ci]), 0.f);
                g = (m > 0) ? g : 0.f;
#pragma unroll
                for (int j = 0; j < CT; ++j)
                    acc[j] = fmaf(g, wt[ci * COUT + j], acc[j]);
            }
        }
    }

    if (MODE == 1) {
        stats_accum_w<COUT, SPLIT, NW>(acc, valid, gw0, ls, stat_out);
        if (valid) {
#pragma unroll
            for (int j = 0; j < CT; ++j) out[(size_t)i * COUT + q * CT + j] = acc[j];
        }
    } else {   // MODE == 2: masked max-pool epilogue, wave-reduced
#pragma unroll
        for (int bb = 0; bb < B; ++bb) {
            float vv[CT];
#pragma unroll
            for (int j = 0; j < CT; ++j) vv[j] = (valid && b == bb) ? acc[j] : -INFINITY;
#pragma unroll
            for (int off = 1; off < 64; off <<= 1) {
#pragma unroll
                for (int j = 0; j < CT; ++j) vv[j] = fmaxf(vv[j], __shfl_xor(vv[j], off, 64));
            }
            if (lane == 0) {
#pragma unroll
                for (int j = 0; j < CT; ++j) atomicMax(&sm[bb * COUT + q * CT + j], encf(vv[j]));
            }
        }
        __syncthreads();
        if (tid < B * COUT) { unsigned e = sm[tid]; if (e) atomicMax(&pooled[tid], e); }
    }
}

// ---------------- DUAL stride-2 conv, wave-q, SGPR weights ---------------------
template <int SPLIT, int TB>
__global__ __launch_bounds__(TB) void k_conv_s2_dual(const float* __restrict__ xs,
                                                     const unsigned long long* __restrict__ stat_in,
                                                     const float* __restrict__ gamma,
                                                     const float* __restrict__ beta,
                                                     const int* __restrict__ cnt_bn,
                                                     const int* __restrict__ map0,
                                                     const int* __restrict__ list1,
                                                     const int* __restrict__ cnt1,
                                                     const float* __restrict__ w1,
                                                     const float* __restrict__ w3,
                                                     float* __restrict__ out1,
                                                     float* __restrict__ out3,
                                                     unsigned long long* __restrict__ stat_out) {
    constexpr int CIN = C0, COUT = C1, CT = COUT / SPLIT;
    constexpr int NW = TB / 64;
    __shared__ float ls[NW * 2 * CT];
    __shared__ float s_sc[CIN], s_sh[CIN];
    const int tid  = threadIdx.x;
    const int lane = tid & 63;
    const int gw0  = blockIdx.x * NW;
    const int n_act = cnt1[0];
    bn_prologue<CIN>(stat_in, gamma, beta, cnt_bn, s_sc, s_sh);
    __syncthreads();

    int gw = __builtin_amdgcn_readfirstlane(gw0 + (tid >> 6));
    int q  = gw % SPLIT;
    int c  = gw / SPLIT;
    int i  = c * 64 + lane;
    bool valid = i < n_act;

    float scr[CIN], shr[CIN];
#pragma unroll
    for (int ci = 0; ci < CIN; ++ci) { scr[ci] = s_sc[ci]; shr[ci] = s_sh[ci]; }

    float acc1[CT], acc3[CT];
#pragma unroll
    for (int j = 0; j < CT; ++j) { acc1[j] = 0.f; acc3[j] = 0.f; }

    if (c * 64 < n_act) {
        int mm[27];
#pragma unroll
        for (int t = 0; t < 27; ++t) mm[t] = 0;
        if (valid) {
            int v = list1[i];
            int z = v % S1; int t2 = v / S1;
            int y = t2 % S1; t2 /= S1;
            int x = t2 % S1; int b = t2 / S1;
#pragma unroll
            for (int kx = 0; kx < 3; ++kx)
#pragma unroll
                for (int ky = 0; ky < 3; ++ky)
#pragma unroll
                    for (int kz = 0; kz < 3; ++kz)
                        mm[(kx * 3 + ky) * 3 + kz] =
                            map0[((b * S + 2 * x + kx) * S + 2 * y + ky) * S + 2 * z + kz];
        }
        const float* wq1 = w1 + q * CT;
        const float* wq3 = w3 + q * CT;
        for (int tap = 0; tap < 27; ++tap) {
            int m = mm[tap];
            float rv[CIN];
            if (m > 0) {
                const float2* r2 = reinterpret_cast<const float2*>(&xs[(size_t)(m - 1) * CIN]);
#pragma unroll
                for (int u = 0; u < CIN / 2; ++u) {
                    float2 f = r2[u];
                    rv[2 * u] = f.x; rv[2 * u + 1] = f.y;
                }
            }
            const float* wt1 = wq1 + (size_t)tap * CIN * COUT;
            const float* wt3 = wq3 + (size_t)tap * CIN * COUT;
#pragma unroll
            for (int ci = 0; ci < CIN; ++ci) {
                float g = fmaxf(fmaf(rv[ci], scr[ci], shr[ci]), 0.f);
                g = (m > 0) ? g : 0.f;
#pragma unroll
                for (int j = 0; j < CT; ++j) {
                    acc1[j] = fmaf(g, wt1[ci * COUT + j], acc1[j]);
                    acc3[j] = fmaf(g, wt3[ci * COUT + j], acc3[j]);
                }
            }
        }
    }
    stats_accum_w<COUT, SPLIT, NW>(acc1, valid, gw0, ls, stat_out);
    if (valid) {
#pragma unroll
        for (int j = 0; j < CT; ++j) {
            out1[(size_t)i * COUT + q * CT + j] = acc1[j];
            out3[(size_t)i * COUT + q * CT + j] = acc3[j];
        }
    }
}

// ---------------- downsampled map + list (L1), block-aggregated append ----------------
__global__ __launch_bounds__(256) void k_map1(const int* __restrict__ map0, int* __restrict__ map1,
                                              int* __restrict__ list1, int* __restrict__ cnt1) {
    int v = blockIdx.x * 256 + threadIdx.x;
    bool valid = v < B * S13;
    bool act = false;
    if (valid) {
        int z = v % S1; int t = v / S1;
        int y = t % S1; t /= S1;
        int x = t % S1; int b = t / S1;
#pragma unroll
        for (int kx = 0; kx < 3; ++kx)
#pragma unroll
            for (int ky = 0; ky < 3; ++ky)
#pragma unroll
                for (int kz = 0; kz < 3; ++kz) {
                    int n = ((b * S + 2 * x + kx) * S + 2 * y + ky) * S + 2 * z + kz;
                    act = act || (map0[n] != 0);
                }
    }
    __shared__ int s_w[4];
    unsigned long long bm = __ballot(act);
    int lane = threadIdx.x & 63, wv = threadIdx.x >> 6;
    int cw = __popcll(bm);
    if (lane == 0) s_w[wv] = cw;
    __syncthreads();
    if (threadIdx.x == 0) {
        int tot = s_w[0] + s_w[1] + s_w[2] + s_w[3];
        int base = tot ? atomicAdd(cnt1, tot) : 0;
        int a = base;
        for (int k = 0; k < 4; ++k) { int c = s_w[k]; s_w[k] = a; a += c; }
    }
    __syncthreads();
    if (valid) {
        if (act) {
            int pos = s_w[wv] + __popcll(bm & ((1ull << lane) - 1ull));
            list1[pos] = v;
            map1[v] = pos + 1;
        } else {
            map1[v] = 0;
        }
    }
}

// ---------------- head: 2-layer MLP on pooled features ----------------
__global__ __launch_bounds__(64) void k_head(const unsigned* __restrict__ pooled,
                                             const float* __restrict__ l1w, const float* __restrict__ l1b,
                                             const float* __restrict__ l2w, const float* __restrict__ l2b,
                                             float* __restrict__ outp) {
    int t = threadIdx.x;               // 64 threads: b = t>>5, j = t&31
    int b = t >> 5, j = t & 31;
    float h = l1b[j];
#pragma unroll
    for (int c = 0; c < C1; ++c) {
        unsigned e = pooled[b * C1 + c];
        float p = (e == 0u) ? 0.f : decf(e);
        p = isfinite(p) ? p : 0.f;
        h = fmaf(l1w[j * C1 + c], p, h);
    }
    float val = l2w[j] * h;
#pragma unroll
    for (int off = 16; off > 0; off >>= 1) val += __shfl_down(val, off, 32);
    if (j == 0) outp[b] = val + l2b[0];
}

extern "C" void kernel_launch(void* const* d_in, const int* in_sizes, int n_in,
                              void* d_out, int out_size, void* d_ws, size_t ws_size,
                              hipStream_t stream) {
    const int*   coords = (const int*)  d_in[0];
    const float* feats  = (const float*)d_in[1];
    const float* w0     = (const float*)d_in[2];
    const float* g0     = (const float*)d_in[3];
    const float* b0     = (const float*)d_in[4];
    const float* ba0_g1 = (const float*)d_in[5];
    const float* ba0_b1 = (const float*)d_in[6];
    const float* ba0_w1 = (const float*)d_in[7];
    const float* ba0_g2 = (const float*)d_in[8];
    const float* ba0_b2 = (const float*)d_in[9];
    const float* ba0_w2 = (const float*)d_in[10];
    const float* ba1_g1 = (const float*)d_in[11];
    const float* ba1_b1 = (const float*)d_in[12];
    const float* ba1_w1 = (const float*)d_in[13];
    const float* ba1_g2 = (const float*)d_in[14];
    const float* ba1_b2 = (const float*)d_in[15];
    const float* ba1_w2 = (const float*)d_in[16];
    const float* bo0_g1 = (const float*)d_in[17];
    const float* bo0_b1 = (const float*)d_in[18];
    const float* bo0_w1 = (const float*)d_in[19];
    const float* bo0_g2 = (const float*)d_in[20];
    const float* bo0_b2 = (const float*)d_in[21];
    const float* bo0_w2 = (const float*)d_in[22];
    const float* bo1_g1 = (const float*)d_in[23];
    const float* bo1_b1 = (const float*)d_in[24];
    const float* bo1_w1 = (const float*)d_in[25];
    const float* bo1_g2 = (const float*)d_in[26];
    const float* bo1_b2 = (const float*)d_in[27];
    const float* bo1_w2 = (const float*)d_in[28];
    const float* dn_g1  = (const float*)d_in[29];
    const float* dn_b1  = (const float*)d_in[30];
    const float* dn_w1  = (const float*)d_in[31];
    const float* dn_g2  = (const float*)d_in[32];
    const float* dn_b2  = (const float*)d_in[33];
    const float* dn_w2  = (const float*)d_in[34];
    const float* dn_w3  = (const float*)d_in[35];
    const float* l1_w   = (const float*)d_in[36];
    const float* l1_b   = (const float*)d_in[37];
    const float* l2_w   = (const float*)d_in[38];
    const float* l2_b   = (const float*)d_in[39];

    char* p = (char*)d_ws;
    auto take = [&](size_t elems) -> float* {
        float* r = (float*)p;
        p += ((elems * 4 + 255) / 256) * 256;
        return r;
    };
    float* grid    = take((size_t)B * S3);
    int*   map0    = (int*)take((size_t)B * S3);
    float* x0      = take((size_t)NPTS * C0);
    float* t0      = take((size_t)NPTS * C0);
    int*   map1    = (int*)take((size_t)B * S13);
    float* t1      = take((size_t)B * S13 * C1);
    float* r1      = take((size_t)B * S13 * C1);
    float* x1      = take((size_t)B * S13 * C1);
    // zero-init region: stats (11 groups x 32 slots x 16 u64) + pooled + cnt
    unsigned long long* stats = (unsigned long long*)take(11 * 32 * STP * 2);
    unsigned* pooled = (unsigned*)take(B * C1);
    int*   cnt     = (int*)take(16);
    char* zero_end = p;
    int*   list0   = (int*)take(NPTS);
    int*   list1   = (int*)take((size_t)B * S13);
    int* cnt0 = cnt;
    int* cnt1 = cnt + 1;
    auto G = [&](int g) { return stats + (size_t)g * 32 * STP; };

    hipMemsetAsync(grid, 0, (size_t)((char*)x0 - (char*)grid), stream);
    hipMemsetAsync(stats, 0, (size_t)(zero_end - (char*)stats), stream);

    constexpr int TB1 = 512;
    constexpr int SPL = 4;                                   // L1 wave-q split
    const int NB_C0 = (NPTS + 255) / 256;                    // 157
    const int NB_L0 = (NPTS * 4 + 255) / 256;                // 625 (lane-q SPLIT=4)
    const int NB_M1 = (B * S13 + 255) / 256;                 // 812
    const int NB_W  = (B * S13 * SPL + TB1 - 1) / TB1;       // 1623 (wave-q SPLIT=4)

    k_scatter<<<NB_C0, 256, 0, stream>>>(coords, feats, grid, map0, list0, cnt0);
    k_conv0s<<<NB_C0, 256, 0, stream>>>(grid, list0, cnt0, w0, x0, G(0));
    k_bn0<<<NB_C0, 256, 0, stream>>>(x0, cnt0, G(0), g0, b0, G(1));

    // ---- basic block ba0 (L0) ----
    k_conv_f<C0, C0, 4, S, 1, 256><<<NB_L0, 256, 0, stream>>>(x0, G(1), ba0_g1, ba0_b1, cnt0,
                                                              map0, list0, cnt0, ba0_w1, nullptr, t0, G(2), nullptr);
    k_conv_f<C0, C0, 4, S, 1, 256><<<NB_L0, 256, 0, stream>>>(t0, G(2), ba0_g2, ba0_b2, cnt0,
                                                              map0, list0, cnt0, ba0_w2, x0, x0, G(3), nullptr);

    // ---- basic block ba1 (L0) ----
    k_conv_f<C0, C0, 4, S, 1, 256><<<NB_L0, 256, 0, stream>>>(x0, G(3), ba1_g1, ba1_b1, cnt0,
                                                              map0, list0, cnt0, ba1_w1, nullptr, t0, G(4), nullptr);
    k_conv_f<C0, C0, 4, S, 1, 256><<<NB_L0, 256, 0, stream>>>(t0, G(4), ba1_g2, ba1_b2, cnt0,
                                                              map0, list0, cnt0, ba1_w2, x0, x0, G(5), nullptr);

    // ---- downsample: one gather, both stride-2 convs ----
    k_map1<<<NB_M1, 256, 0, stream>>>(map0, map1, list1, cnt1);
    k_conv_s2_dual<SPL, TB1><<<NB_W, TB1, 0, stream>>>(x0, G(5), dn_g1, dn_b1, cnt0,
                                                       map0, list1, cnt1, dn_w1, dn_w3, t1, r1, G(6));
    k_conv_w<C1, C1, SPL, 1, TB1><<<NB_W, TB1, 0, stream>>>(t1, G(6), dn_g2, dn_b2, cnt1,
                                                            map1, list1, cnt1, dn_w2, r1, x1, G(7), nullptr);

    // ---- basic block bo0 (L1) ----
    k_conv_w<C1, C1, SPL, 1, TB1><<<NB_W, TB1, 0, stream>>>(x1, G(7), bo0_g1, bo0_b1, cnt1,
                                                            map1, list1, cnt1, bo0_w1, nullptr, t1, G(8), nullptr);
    k_conv_w<C1, C1, SPL, 1, TB1><<<NB_W, TB1, 0, stream>>>(t1, G(8), bo0_g2, bo0_b2, cnt1,
                                                            map1, list1, cnt1, bo0_w2, x1, x1, G(9), nullptr);

    // ---- basic block bo1 (L1), final conv fused with max-pool ----
    k_conv_w<C1, C1, SPL, 1, TB1><<<NB_W, TB1, 0, stream>>>(x1, G(9), bo1_g1, bo1_b1, cnt1,
                                                            map1, list1, cnt1, bo1_w1, nullptr, t1, G(10), nullptr);
    k_conv_w<C1, C1, SPL, 2, TB1><<<NB_W, TB1, 0, stream>>>(t1, G(10), bo1_g2, bo1_b2, cnt1,
                                                            map1, list1, cnt1, bo1_w2, x1, nullptr, nullptr, pooled);

    // ---- head ----
    k_head<<<1, 64, 0, stream>>>(pooled, l1_w, l1_b, l2_w, l2_b, (float*)d_out);
}

// Round 9
// 432.127 us; speedup vs baseline: 1.0742x; 1.0742x over previous
//
#include <hip/hip_runtime.h>
#include <cmath>

constexpr int S    = 95;
constexpr int B    = 2;
constexpr int S3   = S * S * S;          // 857375
constexpr int S1   = 47;
constexpr int S13  = S1 * S1 * S1;       // 103823
constexpr int NPTS = 40000;
constexpr int C0   = 8;
constexpr int C1   = 16;
constexpr float EPS = 1e-4f;
constexpr double SSCALE     = 1048576.0;   // 2^20 fixed-point scale for stats
constexpr double INV_SSCALE = 1.0 / 1048576.0;
constexpr int STP = 16;                    // u64 stride per stat slot (one 128B line)

// order-preserving float<->uint encoding (uint compare == float compare)
__device__ __forceinline__ unsigned encf(float f) {
    unsigned b = __float_as_uint(f);
    return (b & 0x80000000u) ? ~b : (b | 0x80000000u);
}
__device__ __forceinline__ float decf(unsigned e) {
    unsigned b = (e & 0x80000000u) ? (e ^ 0x80000000u) : ~e;
    return __uint_as_float(b);
}

// ---------------- deterministic stats accumulation, lane-q mapping ------------
template <int COUT, int SPLIT, int NW>
__device__ __forceinline__ void stats_accum(const float* acc, bool valid,
                                            float* ls, unsigned long long* stat_out) {
    constexpr int CT = COUT / SPLIT;
    float s0[CT], s1[CT];
#pragma unroll
    for (int j = 0; j < CT; ++j) { float v = valid ? acc[j] : 0.f; s0[j] = v; s1[j] = v * v; }
#pragma unroll
    for (int off = SPLIT; off < 64; off <<= 1) {
#pragma unroll
        for (int j = 0; j < CT; ++j) {
            s0[j] += __shfl_xor(s0[j], off, 64);
            s1[j] += __shfl_xor(s1[j], off, 64);
        }
    }
    int tid = threadIdx.x, lane = tid & 63, wv = tid >> 6;
    if (lane < SPLIT) {
#pragma unroll
        for (int j = 0; j < CT; ++j) {
            ls[wv * 2 * COUT + lane * CT + j]        = s0[j];
            ls[wv * 2 * COUT + COUT + lane * CT + j] = s1[j];
        }
    }
    __syncthreads();
    if (tid < 2 * COUT) {
        float t = 0.f;
#pragma unroll
        for (int w = 0; w < NW; ++w) t += ls[w * 2 * COUT + tid];
        long long q = llrint((double)t * SSCALE);
        atomicAdd(&stat_out[(size_t)tid * STP], (unsigned long long)q);
    }
}

// ---------------- deterministic stats, wave-q mapping, two voxels/thread -------
template <int COUT, int SPLIT, int NW>
__device__ __forceinline__ void stats_accum_w2(const float* a0, const float* a1,
                                               bool v0, bool v1, int gw0,
                                               float* ls, unsigned long long* stat_out) {
    constexpr int CT = COUT / SPLIT;
    float s0[CT], s1[CT];
#pragma unroll
    for (int j = 0; j < CT; ++j) {
        float x0 = v0 ? a0[j] : 0.f;
        float x1 = v1 ? a1[j] : 0.f;
        s0[j] = x0 + x1;
        s1[j] = x0 * x0 + x1 * x1;
    }
#pragma unroll
    for (int off = 1; off < 64; off <<= 1) {
#pragma unroll
        for (int j = 0; j < CT; ++j) {
            s0[j] += __shfl_xor(s0[j], off, 64);
            s1[j] += __shfl_xor(s1[j], off, 64);
        }
    }
    int tid = threadIdx.x, lane = tid & 63, wv = tid >> 6;
    if (lane == 0) {
#pragma unroll
        for (int j = 0; j < CT; ++j) {
            ls[wv * 2 * CT + j]      = s0[j];
            ls[wv * 2 * CT + CT + j] = s1[j];
        }
    }
    __syncthreads();
    if (tid < 2 * COUT) {
        int part = tid / COUT;           // 0 = sum, 1 = sumsq
        int ch   = tid - part * COUT;
        int qc   = ch / CT, jj = ch - qc * CT;
        float t = 0.f;
#pragma unroll
        for (int w = 0; w < NW; ++w)
            if (((gw0 + w) % SPLIT) == qc) t += ls[w * 2 * CT + part * CT + jj];
        long long q = llrint((double)t * SSCALE);
        atomicAdd(&stat_out[(size_t)tid * STP], (unsigned long long)q);
    }
}

// compute per-channel scale/shift from int64 stats into LDS
template <int C>
__device__ __forceinline__ void bn_prologue(const unsigned long long* stat_in,
                                            const float* gamma, const float* beta,
                                            const int* cnt_bn, float* s_sc, float* s_sh) {
    int tid = threadIdx.x;
    if (tid < C) {
        double n   = fmax((double)cnt_bn[0], 1.0);
        double sm  = (double)(long long)stat_in[(size_t)tid * STP] * INV_SSCALE;
        double ssq = (double)(long long)stat_in[(size_t)(C + tid) * STP] * INV_SSCALE;
        double mean = sm / n;
        double var  = ssq / n - mean * mean;
        float sc = gamma[tid] * rsqrtf((float)var + EPS);
        s_sc[tid] = sc;
        s_sh[tid] = fmaf(-(float)mean, sc, beta[tid]);
    }
}

// ---------------- scatter + map0 + list0 (wave-aggregated append) ----------------
__global__ __launch_bounds__(256) void k_scatter(const int* __restrict__ coords,
                                                 const float* __restrict__ feats,
                                                 float* __restrict__ grid, int* __restrict__ map0,
                                                 int* __restrict__ list0, int* __restrict__ cnt0) {
    int i = blockIdx.x * 256 + threadIdx.x;
    bool valid = i < NPTS;
    int v = 0; bool own = false;
    if (valid) {
        int x = coords[i * 4 + 0], y = coords[i * 4 + 1], z = coords[i * 4 + 2], b = coords[i * 4 + 3];
        v = ((b * S + x) * S + y) * S + z;
        atomicAdd(&grid[v], feats[i]);
        own = (atomicCAS(&map0[v], 0, -1) == 0);
    }
    unsigned long long m = __ballot(own);
    int lane = threadIdx.x & 63;
    int base = 0;
    if (lane == 0) { int cw = __popcll(m); if (cw) base = atomicAdd(cnt0, cw); }
    base = __shfl(base, 0, 64);
    if (own) {
        int pos = base + __popcll(m & ((1ull << lane) - 1ull));
        list0[pos] = v;
        map0[v] = pos + 1;
    }
}

// ---------------- conv0: 1 -> 8, SAME, + stats ----------------
__global__ __launch_bounds__(256) void k_conv0s(const float* __restrict__ grid,
                                                const int* __restrict__ list, const int* __restrict__ cnt,
                                                const float* __restrict__ w, float* __restrict__ out,
                                                unsigned long long* __restrict__ stat_out) {
    __shared__ float wl[27 * C0];
    __shared__ float ls[4 * 2 * C0];
    const int tid = threadIdx.x;
    if (tid < 27 * C0) wl[tid] = w[tid];
    __syncthreads();
    int i = blockIdx.x * 256 + tid;
    bool valid = i < cnt[0];
    float acc[C0];
#pragma unroll
    for (int c = 0; c < C0; ++c) acc[c] = 0.f;
    if (valid) {
        int v = list[i];
        int z = v % S; int t = v / S;
        int y = t % S; t /= S;
        int x = t % S; int b = t / S;
        float gg[27];
#pragma unroll
        for (int kx = 0; kx < 3; ++kx) {
            int xx = x + kx - 1;
#pragma unroll
            for (int ky = 0; ky < 3; ++ky) {
                int yy = y + ky - 1;
#pragma unroll
                for (int kz = 0; kz < 3; ++kz) {
                    int zz = z + kz - 1;
                    bool in = (unsigned)xx < (unsigned)S && (unsigned)yy < (unsigned)S && (unsigned)zz < (unsigned)S;
                    gg[(kx * 3 + ky) * 3 + kz] = in ? grid[((b * S + xx) * S + yy) * S + zz] : 0.f;
                }
            }
        }
#pragma unroll
        for (int tap = 0; tap < 27; ++tap) {
            float g = gg[tap];
            if (g != 0.f) {
#pragma unroll
                for (int c = 0; c < C0; ++c) acc[c] = fmaf(g, wl[tap * C0 + c], acc[c]);
            }
        }
    }
    stats_accum<C0, 1, 4>(acc, valid, ls, stat_out);
    if (valid) {
#pragma unroll
        for (int c = 0; c < C0; ++c) out[(size_t)i * C0 + c] = acc[c];
    }
}

// ---------------- bn0: apply BN (from stats) in-place + stats of result --------
__global__ __launch_bounds__(256) void k_bn0(float* __restrict__ xs, const int* __restrict__ cnt,
                                             const unsigned long long* __restrict__ stat_in,
                                             const float* __restrict__ gamma, const float* __restrict__ beta,
                                             unsigned long long* __restrict__ stat_out) {
    __shared__ float ls[4 * 2 * C0];
    __shared__ float s_sc[C0], s_sh[C0];
    bn_prologue<C0>(stat_in, gamma, beta, cnt, s_sc, s_sh);
    __syncthreads();
    int tid = threadIdx.x;
    int i = blockIdx.x * 256 + tid;
    bool valid = i < cnt[0];
    float vals[C0];
#pragma unroll
    for (int c = 0; c < C0; ++c) vals[c] = 0.f;
    if (valid) {
#pragma unroll
        for (int c = 0; c < C0; ++c)
            vals[c] = fmaxf(fmaf(xs[(size_t)i * C0 + c], s_sc[c], s_sh[c]), 0.f);
#pragma unroll
        for (int c = 0; c < C0; ++c) xs[(size_t)i * C0 + c] = vals[c];
    }
    stats_accum<C0, 1, 4>(vals, valid, ls, stat_out);
}

// ---------------- L0 fused conv (lane-q, LDS weights, lane-level tap skip) -----
template <int CIN, int COUT, int SPLIT, int SGOUT, int MODE, int TB>
__global__ __launch_bounds__(TB) void k_conv_f(const float* __restrict__ xs,
                                               const unsigned long long* __restrict__ stat_in,
                                               const float* __restrict__ gamma,
                                               const float* __restrict__ beta,
                                               const int* __restrict__ cnt_bn,
                                               const int* __restrict__ map,
                                               const int* __restrict__ list,
                                               const int* __restrict__ cnt,
                                               const float* __restrict__ w,
                                               const float* __restrict__ res,
                                               float* __restrict__ out,
                                               unsigned long long* __restrict__ stat_out,
                                               unsigned* __restrict__ pooled) {
    constexpr int CT = COUT / SPLIT;
    constexpr int NW = TB / 64;
    __shared__ float wl[27 * CIN * COUT];
    __shared__ float ls[NW * 2 * COUT];
    __shared__ float s_sc[CIN], s_sh[CIN];
    const int tid = threadIdx.x;
    const int n_act = cnt[0];
    bn_prologue<CIN>(stat_in, gamma, beta, cnt_bn, s_sc, s_sh);
    const bool blk_on = (int)(((long)blockIdx.x * TB) / SPLIT) < n_act;
    if (blk_on) {
        for (int idx = tid; idx < 27 * CIN * COUT; idx += TB) wl[idx] = w[idx];
    }
    __syncthreads();

    long gt = (long)blockIdx.x * TB + tid;
    int i = (int)(gt / SPLIT), q = (int)(gt % SPLIT);
    bool valid = i < n_act;

    float acc[CT];
#pragma unroll
    for (int j = 0; j < CT; ++j) acc[j] = 0.f;
    if (valid && res) {
#pragma unroll
        for (int j = 0; j < CT; ++j) acc[j] = res[(size_t)i * COUT + q * CT + j];
    }
    if (valid) {
        int v = list[i];
        int z = v % SGOUT; int t2 = v / SGOUT;
        int y = t2 % SGOUT; t2 /= SGOUT;
        int x = t2 % SGOUT; int b = t2 / SGOUT;
        int mm[27];
#pragma unroll
        for (int kx = 0; kx < 3; ++kx) {
            int xx = x + kx - 1;
#pragma unroll
            for (int ky = 0; ky < 3; ++ky) {
                int yy = y + ky - 1;
#pragma unroll
                for (int kz = 0; kz < 3; ++kz) {
                    int zz = z + kz - 1;
                    bool in = ((unsigned)xx < (unsigned)SGOUT && (unsigned)yy < (unsigned)SGOUT &&
                               (unsigned)zz < (unsigned)SGOUT);
                    mm[(kx * 3 + ky) * 3 + kz] = in ? map[((b * SGOUT + xx) * SGOUT + yy) * SGOUT + zz] : 0;
                }
            }
        }
#pragma unroll
        for (int tap = 0; tap < 27; ++tap) {
            int m = mm[tap];
            if (m > 0) {
                const float* row = &xs[(size_t)(m - 1) * CIN];
                float rv[CIN];
                const float4* r4 = reinterpret_cast<const float4*>(row);
#pragma unroll
                for (int u = 0; u < CIN / 4; ++u) {
                    float4 f = r4[u];
                    rv[4 * u] = f.x; rv[4 * u + 1] = f.y; rv[4 * u + 2] = f.z; rv[4 * u + 3] = f.w;
                }
                const float* wt = &wl[tap * CIN * COUT + q * CT];
#pragma unroll
                for (int ci = 0; ci < CIN; ++ci) {
                    float g = fmaxf(fmaf(rv[ci], s_sc[ci], s_sh[ci]), 0.f);
#pragma unroll
                    for (int j = 0; j < CT; ++j) acc[j] = fmaf(g, wt[ci * COUT + j], acc[j]);
                }
            }
        }
    }
    if (MODE == 1) stats_accum<COUT, SPLIT, NW>(acc, valid, ls, stat_out);
    if (valid) {
#pragma unroll
        for (int j = 0; j < CT; ++j) out[(size_t)i * COUT + q * CT + j] = acc[j];
    }
}

// ---------------- L1 fused conv, wave-q, SGPR weights, TWO voxels/thread -------
// MODE: 1 = out + stats, 2 = pool epilogue (no out)
template <int CIN, int COUT, int SPLIT, int MODE, int TB>
__global__ __launch_bounds__(TB, 2) void k_conv_w(const float* __restrict__ xs,
                                               const unsigned long long* __restrict__ stat_in,
                                               const float* __restrict__ gamma,
                                               const float* __restrict__ beta,
                                               const int* __restrict__ cnt_bn,
                                               const int* __restrict__ map,
                                               const int* __restrict__ list,
                                               const int* __restrict__ cnt,
                                               const float* __restrict__ w,
                                               const float* __restrict__ res,
                                               float* __restrict__ out,
                                               unsigned long long* __restrict__ stat_out,
                                               unsigned* __restrict__ pooled) {
    constexpr int CT = COUT / SPLIT;
    constexpr int NW = TB / 64;
    __shared__ float ls[NW * 2 * CT];
    __shared__ float s_sc[CIN], s_sh[CIN];
    __shared__ unsigned sm[B * COUT];
    const int tid  = threadIdx.x;
    const int lane = tid & 63;
    const int gw0  = blockIdx.x * NW;
    const int n_act = cnt[0];

    if (MODE == 2 && tid < B * COUT) sm[tid] = 0u;
    bn_prologue<CIN>(stat_in, gamma, beta, cnt_bn, s_sc, s_sh);
    __syncthreads();

    int gw = __builtin_amdgcn_readfirstlane(gw0 + (tid >> 6));
    int q  = gw % SPLIT;
    int c  = gw / SPLIT;
    int i0 = c * 128 + lane;
    int i1 = i0 + 64;
    bool va0 = i0 < n_act, va1 = i1 < n_act;

    float scr[CIN], shr[CIN];
#pragma unroll
    for (int ci = 0; ci < CIN; ++ci) { scr[ci] = s_sc[ci]; shr[ci] = s_sh[ci]; }

    float a0[CT], a1[CT];
#pragma unroll
    for (int j = 0; j < CT; ++j) { a0[j] = 0.f; a1[j] = 0.f; }
    int b0 = 0, b1 = 0;

    if (c * 128 < n_act) {                       // wave-uniform early-out for tail
        if (va0 && res) {
#pragma unroll
            for (int j = 0; j < CT; ++j) a0[j] = res[(size_t)i0 * COUT + q * CT + j];
        }
        if (va1 && res) {
#pragma unroll
            for (int j = 0; j < CT; ++j) a1[j] = res[(size_t)i1 * COUT + q * CT + j];
        }
        int mm0[27], mm1[27];
#pragma unroll
        for (int t = 0; t < 27; ++t) { mm0[t] = 0; mm1[t] = 0; }
        if (va0) {
            int v = list[i0];
            int z = v % S1; int t2 = v / S1;
            int y = t2 % S1; t2 /= S1;
            int x = t2 % S1; b0 = t2 / S1;
#pragma unroll
            for (int kx = 0; kx < 3; ++kx) {
                int xx = x + kx - 1;
#pragma unroll
                for (int ky = 0; ky < 3; ++ky) {
                    int yy = y + ky - 1;
#pragma unroll
                    for (int kz = 0; kz < 3; ++kz) {
                        int zz = z + kz - 1;
                        bool in = (unsigned)xx < (unsigned)S1 && (unsigned)yy < (unsigned)S1 &&
                                  (unsigned)zz < (unsigned)S1;
                        mm0[(kx * 3 + ky) * 3 + kz] = in ? map[((b0 * S1 + xx) * S1 + yy) * S1 + zz] : 0;
                    }
                }
            }
        }
        if (va1) {
            int v = list[i1];
            int z = v % S1; int t2 = v / S1;
            int y = t2 % S1; t2 /= S1;
            int x = t2 % S1; b1 = t2 / S1;
#pragma unroll
            for (int kx = 0; kx < 3; ++kx) {
                int xx = x + kx - 1;
#pragma unroll
                for (int ky = 0; ky < 3; ++ky) {
                    int yy = y + ky - 1;
#pragma unroll
                    for (int kz = 0; kz < 3; ++kz) {
                        int zz = z + kz - 1;
                        bool in = (unsigned)xx < (unsigned)S1 && (unsigned)yy < (unsigned)S1 &&
                                  (unsigned)zz < (unsigned)S1;
                        mm1[(kx * 3 + ky) * 3 + kz] = in ? map[((b1 * S1 + xx) * S1 + yy) * S1 + zz] : 0;
                    }
                }
            }
        }
        const float* wq = w + q * CT;            // wave-uniform base
        for (int tap = 0; tap < 27; ++tap) {
            int m0 = mm0[tap], m1 = mm1[tap];
            float rv0[CIN], rv1[CIN];
            if (m0 > 0) {
                const float4* r4 = reinterpret_cast<const float4*>(&xs[(size_t)(m0 - 1) * CIN]);
#pragma unroll
                for (int u = 0; u < CIN / 4; ++u) {
                    float4 f = r4[u];
                    rv0[4 * u] = f.x; rv0[4 * u + 1] = f.y; rv0[4 * u + 2] = f.z; rv0[4 * u + 3] = f.w;
                }
            }
            if (m1 > 0) {
                const float4* r4 = reinterpret_cast<const float4*>(&xs[(size_t)(m1 - 1) * CIN]);
#pragma unroll
                for (int u = 0; u < CIN / 4; ++u) {
                    float4 f = r4[u];
                    rv1[4 * u] = f.x; rv1[4 * u + 1] = f.y; rv1[4 * u + 2] = f.z; rv1[4 * u + 3] = f.w;
                }
            }
            const float* wt = wq + (size_t)tap * CIN * COUT;   // uniform -> s_load
#pragma unroll
            for (int ci = 0; ci < CIN; ++ci) {
                float g0 = fmaxf(fmaf(rv0[ci], scr[ci], shr[ci]), 0.f);
                float g1 = fmaxf(fmaf(rv1[ci], scr[ci], shr[ci]), 0.f);
                g0 = (m0 > 0) ? g0 : 0.f;
                g1 = (m1 > 0) ? g1 : 0.f;
#pragma unroll
                for (int j = 0; j < CT; ++j) {
                    float wv = wt[ci * COUT + j];
                    a0[j] = fmaf(g0, wv, a0[j]);
                    a1[j] = fmaf(g1, wv, a1[j]);
                }
            }
        }
    }

    if (MODE == 1) {
        stats_accum_w2<COUT, SPLIT, NW>(a0, a1, va0, va1, gw0, ls, stat_out);
        if (va0) {
#pragma unroll
            for (int j = 0; j < CT; ++j) out[(size_t)i0 * COUT + q * CT + j] = a0[j];
        }
        if (va1) {
#pragma unroll
            for (int j = 0; j < CT; ++j) out[(size_t)i1 * COUT + q * CT + j] = a1[j];
        }
    } else {   // MODE == 2: masked max-pool epilogue, wave-reduced
#pragma unroll
        for (int bb = 0; bb < B; ++bb) {
            float vv[CT];
#pragma unroll
            for (int j = 0; j < CT; ++j) {
                float x0 = (va0 && b0 == bb) ? a0[j] : -INFINITY;
                float x1 = (va1 && b1 == bb) ? a1[j] : -INFINITY;
                vv[j] = fmaxf(x0, x1);
            }
#pragma unroll
            for (int off = 1; off < 64; off <<= 1) {
#pragma unroll
                for (int j = 0; j < CT; ++j) vv[j] = fmaxf(vv[j], __shfl_xor(vv[j], off, 64));
            }
            if (lane == 0) {
#pragma unroll
                for (int j = 0; j < CT; ++j) atomicMax(&sm[bb * COUT + q * CT + j], encf(vv[j]));
            }
        }
        __syncthreads();
        if (tid < B * COUT) { unsigned e = sm[tid]; if (e) atomicMax(&pooled[tid], e); }
    }
}

// ---------------- DUAL stride-2 conv, wave-q, SGPR weights, TWO voxels/thread --
template <int SPLIT, int TB>
__global__ __launch_bounds__(TB, 2) void k_conv_s2_dual(const float* __restrict__ xs,
                                                     const unsigned long long* __restrict__ stat_in,
                                                     const float* __restrict__ gamma,
                                                     const float* __restrict__ beta,
                                                     const int* __restrict__ cnt_bn,
                                                     const int* __restrict__ map0,
                                                     const int* __restrict__ list1,
                                                     const int* __restrict__ cnt1,
                                                     const float* __restrict__ w1,
                                                     const float* __restrict__ w3,
                                                     float* __restrict__ out1,
                                                     float* __restrict__ out3,
                                                     unsigned long long* __restrict__ stat_out) {
    constexpr int CIN = C0, COUT = C1, CT = COUT / SPLIT;
    constexpr int NW = TB / 64;
    __shared__ float ls[NW * 2 * CT];
    __shared__ float s_sc[CIN], s_sh[CIN];
    const int tid  = threadIdx.x;
    const int lane = tid & 63;
    const int gw0  = blockIdx.x * NW;
    const int n_act = cnt1[0];
    bn_prologue<CIN>(stat_in, gamma, beta, cnt_bn, s_sc, s_sh);
    __syncthreads();

    int gw = __builtin_amdgcn_readfirstlane(gw0 + (tid >> 6));
    int q  = gw % SPLIT;
    int c  = gw / SPLIT;
    int i0 = c * 128 + lane;
    int i1 = i0 + 64;
    bool va0 = i0 < n_act, va1 = i1 < n_act;

    float scr[CIN], shr[CIN];
#pragma unroll
    for (int ci = 0; ci < CIN; ++ci) { scr[ci] = s_sc[ci]; shr[ci] = s_sh[ci]; }

    float p10[CT], p30[CT], p11[CT], p31[CT];
#pragma unroll
    for (int j = 0; j < CT; ++j) { p10[j] = 0.f; p30[j] = 0.f; p11[j] = 0.f; p31[j] = 0.f; }

    if (c * 128 < n_act) {
        int mm0[27], mm1[27];
#pragma unroll
        for (int t = 0; t < 27; ++t) { mm0[t] = 0; mm1[t] = 0; }
        if (va0) {
            int v = list1[i0];
            int z = v % S1; int t2 = v / S1;
            int y = t2 % S1; t2 /= S1;
            int x = t2 % S1; int b = t2 / S1;
#pragma unroll
            for (int kx = 0; kx < 3; ++kx)
#pragma unroll
                for (int ky = 0; ky < 3; ++ky)
#pragma unroll
                    for (int kz = 0; kz < 3; ++kz)
                        mm0[(kx * 3 + ky) * 3 + kz] =
                            map0[((b * S + 2 * x + kx) * S + 2 * y + ky) * S + 2 * z + kz];
        }
        if (va1) {
            int v = list1[i1];
            int z = v % S1; int t2 = v / S1;
            int y = t2 % S1; t2 /= S1;
            int x = t2 % S1; int b = t2 / S1;
#pragma unroll
            for (int kx = 0; kx < 3; ++kx)
#pragma unroll
                for (int ky = 0; ky < 3; ++ky)
#pragma unroll
                    for (int kz = 0; kz < 3; ++kz)
                        mm1[(kx * 3 + ky) * 3 + kz] =
                            map0[((b * S + 2 * x + kx) * S + 2 * y + ky) * S + 2 * z + kz];
        }
        const float* wq1 = w1 + q * CT;
        const float* wq3 = w3 + q * CT;
        for (int tap = 0; tap < 27; ++tap) {
            int m0 = mm0[tap], m1 = mm1[tap];
            float rv0[CIN], rv1[CIN];
            if (m0 > 0) {
                const float4* r4 = reinterpret_cast<const float4*>(&xs[(size_t)(m0 - 1) * CIN]);
#pragma unroll
                for (int u = 0; u < CIN / 4; ++u) {
                    float4 f = r4[u];
                    rv0[4 * u] = f.x; rv0[4 * u + 1] = f.y; rv0[4 * u + 2] = f.z; rv0[4 * u + 3] = f.w;
                }
            }
            if (m1 > 0) {
                const float4* r4 = reinterpret_cast<const float4*>(&xs[(size_t)(m1 - 1) * CIN]);
#pragma unroll
                for (int u = 0; u < CIN / 4; ++u) {
                    float4 f = r4[u];
                    rv1[4 * u] = f.x; rv1[4 * u + 1] = f.y; rv1[4 * u + 2] = f.z; rv1[4 * u + 3] = f.w;
                }
            }
            const float* wt1 = wq1 + (size_t)tap * CIN * COUT;
            const float* wt3 = wq3 + (size_t)tap * CIN * COUT;
#pragma unroll
            for (int ci = 0; ci < CIN; ++ci) {
                float g0 = fmaxf(fmaf(rv0[ci], scr[ci], shr[ci]), 0.f);
                float g1 = fmaxf(fmaf(rv1[ci], scr[ci], shr[ci]), 0.f);
                g0 = (m0 > 0) ? g0 : 0.f;
                g1 = (m1 > 0) ? g1 : 0.f;
#pragma unroll
                for (int j = 0; j < CT; ++j) {
                    float wv1 = wt1[ci * COUT + j];
                    float wv3 = wt3[ci * COUT + j];
                    p10[j] = fmaf(g0, wv1, p10[j]);
                    p11[j] = fmaf(g1, wv1, p11[j]);
                    p30[j] = fmaf(g0, wv3, p30[j]);
                    p31[j] = fmaf(g1, wv3, p31[j]);
                }
            }
        }
    }
    stats_accum_w2<COUT, SPLIT, NW>(p10, p11, va0, va1, gw0, ls, stat_out);
    if (va0) {
#pragma unroll
        for (int j = 0; j < CT; ++j) {
            out1[(size_t)i0 * COUT + q * CT + j] = p10[j];
            out3[(size_t)i0 * COUT + q * CT + j] = p30[j];
        }
    }
    if (va1) {
#pragma unroll
        for (int j = 0; j < CT; ++j) {
            out1[(size_t)i1 * COUT + q * CT + j] = p11[j];
            out3[(size_t)i1 * COUT + q * CT + j] = p31[j];
        }
    }
}

// ---------------- downsampled map + list (L1), block-aggregated append ----------------
__global__ __launch_bounds__(256) void k_map1(const int* __restrict__ map0, int* __restrict__ map1,
                                              int* __restrict__ list1, int* __restrict__ cnt1) {
    int v = blockIdx.x * 256 + threadIdx.x;
    bool valid = v < B * S13;
    bool act = false;
    if (valid) {
        int z = v % S1; int t = v / S1;
        int y = t % S1; t /= S1;
        int x = t % S1; int b = t / S1;
#pragma unroll
        for (int kx = 0; kx < 3; ++kx)
#pragma unroll
            for (int ky = 0; ky < 3; ++ky)
#pragma unroll
                for (int kz = 0; kz < 3; ++kz) {
                    int n = ((b * S + 2 * x + kx) * S + 2 * y + ky) * S + 2 * z + kz;
                    act = act || (map0[n] != 0);
                }
    }
    __shared__ int s_w[4];
    unsigned long long bm = __ballot(act);
    int lane = threadIdx.x & 63, wv = threadIdx.x >> 6;
    int cw = __popcll(bm);
    if (lane == 0) s_w[wv] = cw;
    __syncthreads();
    if (threadIdx.x == 0) {
        int tot = s_w[0] + s_w[1] + s_w[2] + s_w[3];
        int base = tot ? atomicAdd(cnt1, tot) : 0;
        int a = base;
        for (int k = 0; k < 4; ++k) { int c = s_w[k]; s_w[k] = a; a += c; }
    }
    __syncthreads();
    if (valid) {
        if (act) {
            int pos = s_w[wv] + __popcll(bm & ((1ull << lane) - 1ull));
            list1[pos] = v;
            map1[v] = pos + 1;
        } else {
            map1[v] = 0;
        }
    }
}

// ---------------- head: 2-layer MLP on pooled features ----------------
__global__ __launch_bounds__(64) void k_head(const unsigned* __restrict__ pooled,
                                             const float* __restrict__ l1w, const float* __restrict__ l1b,
                                             const float* __restrict__ l2w, const float* __restrict__ l2b,
                                             float* __restrict__ outp) {
    int t = threadIdx.x;               // 64 threads: b = t>>5, j = t&31
    int b = t >> 5, j = t & 31;
    float h = l1b[j];
#pragma unroll
    for (int c = 0; c < C1; ++c) {
        unsigned e = pooled[b * C1 + c];
        float p = (e == 0u) ? 0.f : decf(e);
        p = isfinite(p) ? p : 0.f;
        h = fmaf(l1w[j * C1 + c], p, h);
    }
    float val = l2w[j] * h;
#pragma unroll
    for (int off = 16; off > 0; off >>= 1) val += __shfl_down(val, off, 32);
    if (j == 0) outp[b] = val + l2b[0];
}

extern "C" void kernel_launch(void* const* d_in, const int* in_sizes, int n_in,
                              void* d_out, int out_size, void* d_ws, size_t ws_size,
                              hipStream_t stream) {
    const int*   coords = (const int*)  d_in[0];
    const float* feats  = (const float*)d_in[1];
    const float* w0     = (const float*)d_in[2];
    const float* g0     = (const float*)d_in[3];
    const float* b0     = (const float*)d_in[4];
    const float* ba0_g1 = (const float*)d_in[5];
    const float* ba0_b1 = (const float*)d_in[6];
    const float* ba0_w1 = (const float*)d_in[7];
    const float* ba0_g2 = (const float*)d_in[8];
    const float* ba0_b2 = (const float*)d_in[9];
    const float* ba0_w2 = (const float*)d_in[10];
    const float* ba1_g1 = (const float*)d_in[11];
    const float* ba1_b1 = (const float*)d_in[12];
    const float* ba1_w1 = (const float*)d_in[13];
    const float* ba1_g2 = (const float*)d_in[14];
    const float* ba1_b2 = (const float*)d_in[15];
    const float* ba1_w2 = (const float*)d_in[16];
    const float* bo0_g1 = (const float*)d_in[17];
    const float* bo0_b1 = (const float*)d_in[18];
    const float* bo0_w1 = (const float*)d_in[19];
    const float* bo0_g2 = (const float*)d_in[20];
    const float* bo0_b2 = (const float*)d_in[21];
    const float* bo0_w2 = (const float*)d_in[22];
    const float* bo1_g1 = (const float*)d_in[23];
    const float* bo1_b1 = (const float*)d_in[24];
    const float* bo1_w1 = (const float*)d_in[25];
    const float* bo1_g2 = (const float*)d_in[26];
    const float* bo1_b2 = (const float*)d_in[27];
    const float* bo1_w2 = (const float*)d_in[28];
    const float* dn_g1  = (const float*)d_in[29];
    const float* dn_b1  = (const float*)d_in[30];
    const float* dn_w1  = (const float*)d_in[31];
    const float* dn_g2  = (const float*)d_in[32];
    const float* dn_b2  = (const float*)d_in[33];
    const float* dn_w2  = (const float*)d_in[34];
    const float* dn_w3  = (const float*)d_in[35];
    const float* l1_w   = (const float*)d_in[36];
    const float* l1_b   = (const float*)d_in[37];
    const float* l2_w   = (const float*)d_in[38];
    const float* l2_b   = (const float*)d_in[39];

    char* p = (char*)d_ws;
    auto take = [&](size_t elems) -> float* {
        float* r = (float*)p;
        p += ((elems * 4 + 255) / 256) * 256;
        return r;
    };
    float* grid    = take((size_t)B * S3);
    int*   map0    = (int*)take((size_t)B * S3);
    float* x0      = take((size_t)NPTS * C0);
    float* t0      = take((size_t)NPTS * C0);
    int*   map1    = (int*)take((size_t)B * S13);
    float* t1      = take((size_t)B * S13 * C1);
    float* r1      = take((size_t)B * S13 * C1);
    float* x1      = take((size_t)B * S13 * C1);
    // zero-init region: stats (11 groups x 32 slots x 16 u64) + pooled + cnt
    unsigned long long* stats = (unsigned long long*)take(11 * 32 * STP * 2);
    unsigned* pooled = (unsigned*)take(B * C1);
    int*   cnt     = (int*)take(16);
    char* zero_end = p;
    int*   list0   = (int*)take(NPTS);
    int*   list1   = (int*)take((size_t)B * S13);
    int* cnt0 = cnt;
    int* cnt1 = cnt + 1;
    auto G = [&](int g) { return stats + (size_t)g * 32 * STP; };

    hipMemsetAsync(grid, 0, (size_t)((char*)x0 - (char*)grid), stream);
    hipMemsetAsync(stats, 0, (size_t)(zero_end - (char*)stats), stream);

    constexpr int TBW = 256;                                 // L1 conv block (4 waves)
    constexpr int SPL = 2;                                   // L1 wave-q split
    const int NB_C0 = (NPTS + 255) / 256;                    // 157
    const int NB_L0 = (NPTS * 4 + 255) / 256;                // 625 (lane-q SPLIT=4)
    const int NB_M1 = (B * S13 + 255) / 256;                 // 812
    const int CHUNKS = (B * S13 + 127) / 128;                // 1623 (128 voxels/wave)
    const int NB_W  = (CHUNKS * SPL + (TBW / 64) - 1) / (TBW / 64);   // 812 blocks

    k_scatter<<<NB_C0, 256, 0, stream>>>(coords, feats, grid, map0, list0, cnt0);
    k_conv0s<<<NB_C0, 256, 0, stream>>>(grid, list0, cnt0, w0, x0, G(0));
    k_bn0<<<NB_C0, 256, 0, stream>>>(x0, cnt0, G(0), g0, b0, G(1));

    // ---- basic block ba0 (L0) ----
    k_conv_f<C0, C0, 4, S, 1, 256><<<NB_L0, 256, 0, stream>>>(x0, G(1), ba0_g1, ba0_b1, cnt0,
                                                              map0, list0, cnt0, ba0_w1, nullptr, t0, G(2), nullptr);
    k_conv_f<C0, C0, 4, S, 1, 256><<<NB_L0, 256, 0, stream>>>(t0, G(2), ba0_g2, ba0_b2, cnt0,
                                                              map0, list0, cnt0, ba0_w2, x0, x0, G(3), nullptr);

    // ---- basic block ba1 (L0) ----
    k_conv_f<C0, C0, 4, S, 1, 256><<<NB_L0, 256, 0, stream>>>(x0, G(3), ba1_g1, ba1_b1, cnt0,
                                                              map0, list0, cnt0, ba1_w1, nullptr, t0, G(4), nullptr);
    k_conv_f<C0, C0, 4, S, 1, 256><<<NB_L0, 256, 0, stream>>>(t0, G(4), ba1_g2, ba1_b2, cnt0,
                                                              map0, list0, cnt0, ba1_w2, x0, x0, G(5), nullptr);

    // ---- downsample: one gather, both stride-2 convs ----
    k_map1<<<NB_M1, 256, 0, stream>>>(map0, map1, list1, cnt1);
    k_conv_s2_dual<SPL, TBW><<<NB_W, TBW, 0, stream>>>(x0, G(5), dn_g1, dn_b1, cnt0,
                                                       map0, list1, cnt1, dn_w1, dn_w3, t1, r1, G(6));
    k_conv_w<C1, C1, SPL, 1, TBW><<<NB_W, TBW, 0, stream>>>(t1, G(6), dn_g2, dn_b2, cnt1,
                                                            map1, list1, cnt1, dn_w2, r1, x1, G(7), nullptr);

    // ---- basic block bo0 (L1) ----
    k_conv_w<C1, C1, SPL, 1, TBW><<<NB_W, TBW, 0, stream>>>(x1, G(7), bo0_g1, bo0_b1, cnt1,
                                                            map1, list1, cnt1, bo0_w1, nullptr, t1, G(8), nullptr);
    k_conv_w<C1, C1, SPL, 1, TBW><<<NB_W, TBW, 0, stream>>>(t1, G(8), bo0_g2, bo0_b2, cnt1,
                                                            map1, list1, cnt1, bo0_w2, x1, x1, G(9), nullptr);

    // ---- basic block bo1 (L1), final conv fused with max-pool ----
    k_conv_w<C1, C1, SPL, 1, TBW><<<NB_W, TBW, 0, stream>>>(x1, G(9), bo1_g1, bo1_b1, cnt1,
                                                            map1, list1, cnt1, bo1_w1, nullptr, t1, G(10), nullptr);
    k_conv_w<C1, C1, SPL, 2, TBW><<<NB_W, TBW, 0, stream>>>(t1, G(10), bo1_g2, bo1_b2, cnt1,
                                                            map1, list1, cnt1, bo1_w2, x1, nullptr, nullptr, pooled);

    // ---- head ----
    k_head<<<1, 64, 0, stream>>>(pooled, l1_w, l1_b, l2_w, l2_b, (float*)d_out);
}

// Round 10
// 364.343 us; speedup vs baseline: 1.2741x; 1.1860x over previous
//
#include <hip/hip_runtime.h>
#include <cmath>

constexpr int S    = 95;
constexpr int B    = 2;
constexpr int S3   = S * S * S;          // 857375
constexpr int S1   = 47;
constexpr int S13  = S1 * S1 * S1;       // 103823
constexpr int NPTS = 40000;
constexpr int C0   = 8;
constexpr int C1   = 16;
constexpr float EPS = 1e-4f;
constexpr double SSCALE     = 1048576.0;   // 2^20 fixed-point scale for stats
constexpr double INV_SSCALE = 1.0 / 1048576.0;
constexpr int STP = 16;                    // u64 stride per stat slot (one 128B line)

// order-preserving float<->uint encoding (uint compare == float compare)
__device__ __forceinline__ unsigned encf(float f) {
    unsigned b = __float_as_uint(f);
    return (b & 0x80000000u) ? ~b : (b | 0x80000000u);
}
__device__ __forceinline__ float decf(unsigned e) {
    unsigned b = (e & 0x80000000u) ? (e ^ 0x80000000u) : ~e;
    return __uint_as_float(b);
}

// ---------------- deterministic stats accumulation, lane-q mapping ------------
template <int COUT, int SPLIT, int NW>
__device__ __forceinline__ void stats_accum(const float* acc, bool valid,
                                            float* ls, unsigned long long* stat_out) {
    constexpr int CT = COUT / SPLIT;
    float s0[CT], s1[CT];
#pragma unroll
    for (int j = 0; j < CT; ++j) { float v = valid ? acc[j] : 0.f; s0[j] = v; s1[j] = v * v; }
#pragma unroll
    for (int off = SPLIT; off < 64; off <<= 1) {
#pragma unroll
        for (int j = 0; j < CT; ++j) {
            s0[j] += __shfl_xor(s0[j], off, 64);
            s1[j] += __shfl_xor(s1[j], off, 64);
        }
    }
    int tid = threadIdx.x, lane = tid & 63, wv = tid >> 6;
    if (lane < SPLIT) {
#pragma unroll
        for (int j = 0; j < CT; ++j) {
            ls[wv * 2 * COUT + lane * CT + j]        = s0[j];
            ls[wv * 2 * COUT + COUT + lane * CT + j] = s1[j];
        }
    }
    __syncthreads();
    if (tid < 2 * COUT) {
        float t = 0.f;
#pragma unroll
        for (int w = 0; w < NW; ++w) t += ls[w * 2 * COUT + tid];
        long long q = llrint((double)t * SSCALE);
        atomicAdd(&stat_out[(size_t)tid * STP], (unsigned long long)q);
    }
}

// ---------------- deterministic stats accumulation, wave-q mapping ------------
template <int COUT, int SPLIT, int NW>
__device__ __forceinline__ void stats_accum_w(const float* acc, bool valid, int gw0,
                                              float* ls, unsigned long long* stat_out) {
    constexpr int CT = COUT / SPLIT;
    float s0[CT], s1[CT];
#pragma unroll
    for (int j = 0; j < CT; ++j) { float v = valid ? acc[j] : 0.f; s0[j] = v; s1[j] = v * v; }
#pragma unroll
    for (int off = 1; off < 64; off <<= 1) {
#pragma unroll
        for (int j = 0; j < CT; ++j) {
            s0[j] += __shfl_xor(s0[j], off, 64);
            s1[j] += __shfl_xor(s1[j], off, 64);
        }
    }
    int tid = threadIdx.x, lane = tid & 63, wv = tid >> 6;
    if (lane == 0) {
#pragma unroll
        for (int j = 0; j < CT; ++j) {
            ls[wv * 2 * CT + j]      = s0[j];
            ls[wv * 2 * CT + CT + j] = s1[j];
        }
    }
    __syncthreads();
    if (tid < 2 * COUT) {
        int part = tid / COUT;           // 0 = sum, 1 = sumsq
        int ch   = tid - part * COUT;
        int qc   = ch / CT, jj = ch - qc * CT;
        float t = 0.f;
#pragma unroll
        for (int w = 0; w < NW; ++w)
            if (((gw0 + w) % SPLIT) == qc) t += ls[w * 2 * CT + part * CT + jj];
        long long q = llrint((double)t * SSCALE);
        atomicAdd(&stat_out[(size_t)tid * STP], (unsigned long long)q);
    }
}

// compute per-channel scale/shift from int64 stats into LDS
template <int C>
__device__ __forceinline__ void bn_prologue(const unsigned long long* stat_in,
                                            const float* gamma, const float* beta,
                                            const int* cnt_bn, float* s_sc, float* s_sh) {
    int tid = threadIdx.x;
    if (tid < C) {
        double n   = fmax((double)cnt_bn[0], 1.0);
        double sm  = (double)(long long)stat_in[(size_t)tid * STP] * INV_SSCALE;
        double ssq = (double)(long long)stat_in[(size_t)(C + tid) * STP] * INV_SSCALE;
        double mean = sm / n;
        double var  = ssq / n - mean * mean;
        float sc = gamma[tid] * rsqrtf((float)var + EPS);
        s_sc[tid] = sc;
        s_sh[tid] = fmaf(-(float)mean, sc, beta[tid]);
    }
}

// ---------------- scatter + map0 + list0 (wave-aggregated append) ----------------
__global__ __launch_bounds__(256) void k_scatter(const int* __restrict__ coords,
                                                 const float* __restrict__ feats,
                                                 float* __restrict__ grid, int* __restrict__ map0,
                                                 int* __restrict__ list0, int* __restrict__ cnt0) {
    int i = blockIdx.x * 256 + threadIdx.x;
    bool valid = i < NPTS;
    int v = 0; bool own = false;
    if (valid) {
        int x = coords[i * 4 + 0], y = coords[i * 4 + 1], z = coords[i * 4 + 2], b = coords[i * 4 + 3];
        v = ((b * S + x) * S + y) * S + z;
        atomicAdd(&grid[v], feats[i]);
        own = (atomicCAS(&map0[v], 0, -1) == 0);
    }
    unsigned long long m = __ballot(own);
    int lane = threadIdx.x & 63;
    int base = 0;
    if (lane == 0) { int cw = __popcll(m); if (cw) base = atomicAdd(cnt0, cw); }
    base = __shfl(base, 0, 64);
    if (own) {
        int pos = base + __popcll(m & ((1ull << lane) - 1ull));
        list0[pos] = v;
        map0[v] = pos + 1;
    }
}

// ---------------- conv0: 1 -> 8, SAME, + stats ----------------
__global__ __launch_bounds__(256) void k_conv0s(const float* __restrict__ grid,
                                                const int* __restrict__ list, const int* __restrict__ cnt,
                                                const float* __restrict__ w, float* __restrict__ out,
                                                unsigned long long* __restrict__ stat_out) {
    __shared__ float wl[27 * C0];
    __shared__ float ls[4 * 2 * C0];
    const int tid = threadIdx.x;
    if (tid < 27 * C0) wl[tid] = w[tid];
    __syncthreads();
    int i = blockIdx.x * 256 + tid;
    bool valid = i < cnt[0];
    float acc[C0];
#pragma unroll
    for (int c = 0; c < C0; ++c) acc[c] = 0.f;
    if (valid) {
        int v = list[i];
        int z = v % S; int t = v / S;
        int y = t % S; t /= S;
        int x = t % S; int b = t / S;
        float gg[27];
#pragma unroll
        for (int kx = 0; kx < 3; ++kx) {
            int xx = x + kx - 1;
#pragma unroll
            for (int ky = 0; ky < 3; ++ky) {
                int yy = y + ky - 1;
#pragma unroll
                for (int kz = 0; kz < 3; ++kz) {
                    int zz = z + kz - 1;
                    bool in = (unsigned)xx < (unsigned)S && (unsigned)yy < (unsigned)S && (unsigned)zz < (unsigned)S;
                    gg[(kx * 3 + ky) * 3 + kz] = in ? grid[((b * S + xx) * S + yy) * S + zz] : 0.f;
                }
            }
        }
#pragma unroll
        for (int tap = 0; tap < 27; ++tap) {
            float g = gg[tap];
            if (g != 0.f) {
#pragma unroll
                for (int c = 0; c < C0; ++c) acc[c] = fmaf(g, wl[tap * C0 + c], acc[c]);
            }
        }
    }
    stats_accum<C0, 1, 4>(acc, valid, ls, stat_out);
    if (valid) {
#pragma unroll
        for (int c = 0; c < C0; ++c) out[(size_t)i * C0 + c] = acc[c];
    }
}

// ---------------- bn0: apply BN (from stats) in-place + stats of result --------
__global__ __launch_bounds__(256) void k_bn0(float* __restrict__ xs, const int* __restrict__ cnt,
                                             const unsigned long long* __restrict__ stat_in,
                                             const float* __restrict__ gamma, const float* __restrict__ beta,
                                             unsigned long long* __restrict__ stat_out) {
    __shared__ float ls[4 * 2 * C0];
    __shared__ float s_sc[C0], s_sh[C0];
    bn_prologue<C0>(stat_in, gamma, beta, cnt, s_sc, s_sh);
    __syncthreads();
    int tid = threadIdx.x;
    int i = blockIdx.x * 256 + tid;
    bool valid = i < cnt[0];
    float vals[C0];
#pragma unroll
    for (int c = 0; c < C0; ++c) vals[c] = 0.f;
    if (valid) {
#pragma unroll
        for (int c = 0; c < C0; ++c)
            vals[c] = fmaxf(fmaf(xs[(size_t)i * C0 + c], s_sc[c], s_sh[c]), 0.f);
#pragma unroll
        for (int c = 0; c < C0; ++c) xs[(size_t)i * C0 + c] = vals[c];
    }
    stats_accum<C0, 1, 4>(vals, valid, ls, stat_out);
}

// ---------------- L0 fused conv (lane-q, LDS weights, lane-level tap skip) -----
template <int CIN, int COUT, int SPLIT, int SGOUT, int MODE, int TB>
__global__ __launch_bounds__(TB) void k_conv_f(const float* __restrict__ xs,
                                               const unsigned long long* __restrict__ stat_in,
                                               const float* __restrict__ gamma,
                                               const float* __restrict__ beta,
                                               const int* __restrict__ cnt_bn,
                                               const int* __restrict__ map,
                                               const int* __restrict__ list,
                                               const int* __restrict__ cnt,
                                               const float* __restrict__ w,
                                               const float* __restrict__ res,
                                               float* __restrict__ out,
                                               unsigned long long* __restrict__ stat_out,
                                               unsigned* __restrict__ pooled) {
    constexpr int CT = COUT / SPLIT;
    constexpr int NW = TB / 64;
    __shared__ float wl[27 * CIN * COUT];
    __shared__ float ls[NW * 2 * COUT];
    __shared__ float s_sc[CIN], s_sh[CIN];
    const int tid = threadIdx.x;
    const int n_act = cnt[0];
    bn_prologue<CIN>(stat_in, gamma, beta, cnt_bn, s_sc, s_sh);
    const bool blk_on = (int)(((long)blockIdx.x * TB) / SPLIT) < n_act;
    if (blk_on) {
        for (int idx = tid; idx < 27 * CIN * COUT; idx += TB) wl[idx] = w[idx];
    }
    __syncthreads();

    long gt = (long)blockIdx.x * TB + tid;
    int i = (int)(gt / SPLIT), q = (int)(gt % SPLIT);
    bool valid = i < n_act;

    float acc[CT];
#pragma unroll
    for (int j = 0; j < CT; ++j) acc[j] = 0.f;
    if (valid && res) {
#pragma unroll
        for (int j = 0; j < CT; ++j) acc[j] = res[(size_t)i * COUT + q * CT + j];
    }
    if (valid) {
        int v = list[i];
        int z = v % SGOUT; int t2 = v / SGOUT;
        int y = t2 % SGOUT; t2 /= SGOUT;
        int x = t2 % SGOUT; int b = t2 / SGOUT;
        int mm[27];
#pragma unroll
        for (int kx = 0; kx < 3; ++kx) {
            int xx = x + kx - 1;
#pragma unroll
            for (int ky = 0; ky < 3; ++ky) {
                int yy = y + ky - 1;
#pragma unroll
                for (int kz = 0; kz < 3; ++kz) {
                    int zz = z + kz - 1;
                    bool in = ((unsigned)xx < (unsigned)SGOUT && (unsigned)yy < (unsigned)SGOUT &&
                               (unsigned)zz < (unsigned)SGOUT);
                    mm[(kx * 3 + ky) * 3 + kz] = in ? map[((b * SGOUT + xx) * SGOUT + yy) * SGOUT + zz] : 0;
                }
            }
        }
#pragma unroll
        for (int tap = 0; tap < 27; ++tap) {
            int m = mm[tap];
            if (m > 0) {
                const float* row = &xs[(size_t)(m - 1) * CIN];
                float rv[CIN];
                const float4* r4 = reinterpret_cast<const float4*>(row);
#pragma unroll
                for (int u = 0; u < CIN / 4; ++u) {
                    float4 f = r4[u];
                    rv[4 * u] = f.x; rv[4 * u + 1] = f.y; rv[4 * u + 2] = f.z; rv[4 * u + 3] = f.w;
                }
                const float* wt = &wl[tap * CIN * COUT + q * CT];
#pragma unroll
                for (int ci = 0; ci < CIN; ++ci) {
                    float g = fmaxf(fmaf(rv[ci], s_sc[ci], s_sh[ci]), 0.f);
#pragma unroll
                    for (int j = 0; j < CT; ++j) acc[j] = fmaf(g, wt[ci * COUT + j], acc[j]);
                }
            }
        }
    }
    if (MODE == 1) stats_accum<COUT, SPLIT, NW>(acc, valid, ls, stat_out);
    if (valid) {
#pragma unroll
        for (int j = 0; j < CT; ++j) out[(size_t)i * COUT + q * CT + j] = acc[j];
    }
}

// ---------------- L1 fused conv, wave-q, SGPR weights, branch-free pipelined ---
// MODE: 1 = out + stats, 2 = pool epilogue (no out)
template <int CIN, int COUT, int SPLIT, int MODE, int TB>
__global__ __launch_bounds__(TB, 2) void k_conv_w(const float* __restrict__ xs,
                                               const unsigned long long* __restrict__ stat_in,
                                               const float* __restrict__ gamma,
                                               const float* __restrict__ beta,
                                               const int* __restrict__ cnt_bn,
                                               const int* __restrict__ map,
                                               const int* __restrict__ list,
                                               const int* __restrict__ cnt,
                                               const float* __restrict__ w,
                                               const float* __restrict__ res,
                                               float* __restrict__ out,
                                               unsigned long long* __restrict__ stat_out,
                                               unsigned* __restrict__ pooled) {
    constexpr int CT = COUT / SPLIT;
    constexpr int NW = TB / 64;
    constexpr int NV4 = CIN / 4;
    __shared__ float ls[NW * 2 * CT];
    __shared__ float s_sc[CIN], s_sh[CIN];
    __shared__ unsigned sm[B * COUT];
    const int tid  = threadIdx.x;
    const int lane = tid & 63;
    const int gw0  = blockIdx.x * NW;
    const int n_act = cnt[0];

    if (MODE == 2 && tid < B * COUT) sm[tid] = 0u;
    bn_prologue<CIN>(stat_in, gamma, beta, cnt_bn, s_sc, s_sh);
    __syncthreads();

    int gw = __builtin_amdgcn_readfirstlane(gw0 + (tid >> 6));
    int q  = gw % SPLIT;
    int c  = gw / SPLIT;
    int i  = c * 64 + lane;
    bool valid = i < n_act;

    float scr[CIN], shr[CIN];
#pragma unroll
    for (int ci = 0; ci < CIN; ++ci) { scr[ci] = s_sc[ci]; shr[ci] = s_sh[ci]; }

    float acc[CT];
#pragma unroll
    for (int j = 0; j < CT; ++j) acc[j] = 0.f;
    int b = 0;

    if (c * 64 < n_act) {                       // wave-uniform early-out for tail
        int ii = valid ? i : (n_act - 1);       // clamp: all addresses legal
        if (valid && res) {
#pragma unroll
            for (int j = 0; j < CT; ++j) acc[j] = res[(size_t)i * COUT + q * CT + j];
        }
        int v = list[ii];
        int z = v % S1; int t2 = v / S1;
        int y = t2 % S1; t2 /= S1;
        int x = t2 % S1; b = t2 / S1;
        int mm[27];
#pragma unroll
        for (int kx = 0; kx < 3; ++kx) {
            int xx = x + kx - 1;
#pragma unroll
            for (int ky = 0; ky < 3; ++ky) {
                int yy = y + ky - 1;
#pragma unroll
                for (int kz = 0; kz < 3; ++kz) {
                    int zz = z + kz - 1;
                    bool in = (unsigned)xx < (unsigned)S1 && (unsigned)yy < (unsigned)S1 &&
                              (unsigned)zz < (unsigned)S1;
                    mm[(kx * 3 + ky) * 3 + kz] = in ? map[((b * S1 + xx) * S1 + yy) * S1 + zz] : 0;
                }
            }
        }
        // branch-free pipelined gather: rows loaded unconditionally from clamped
        // addresses; next tap's rows issued before current tap's FMAs.
        auto rowp = [&](int m) {
            return reinterpret_cast<const float4*>(&xs[(size_t)(m > 0 ? m - 1 : 0) * CIN]);
        };
        float4 cr[NV4];
        {
            const float4* r = rowp(mm[0]);
#pragma unroll
            for (int u = 0; u < NV4; ++u) cr[u] = r[u];
        }
        const float* wq = w + q * CT;            // wave-uniform base
        for (int tap = 0; tap < 27; ++tap) {
            float4 nr[NV4];
            {
                const float4* r = rowp(mm[tap < 26 ? tap + 1 : 26]);
#pragma unroll
                for (int u = 0; u < NV4; ++u) nr[u] = r[u];
            }
            int m = mm[tap];
            const float* wt = wq + (size_t)tap * CIN * COUT;   // uniform -> s_load
            float rv[CIN];
#pragma unroll
            for (int u = 0; u < NV4; ++u) {
                rv[4 * u] = cr[u].x; rv[4 * u + 1] = cr[u].y;
                rv[4 * u + 2] = cr[u].z; rv[4 * u + 3] = cr[u].w;
            }
#pragma unroll
            for (int ci = 0; ci < CIN; ++ci) {
                float g = fmaxf(fmaf(rv[ci], scr[ci], shr[ci]), 0.f);
                g = (m > 0) ? g : 0.f;
#pragma unroll
                for (int j = 0; j < CT; ++j)
                    acc[j] = fmaf(g, wt[ci * COUT + j], acc[j]);
            }
#pragma unroll
            for (int u = 0; u < NV4; ++u) cr[u] = nr[u];
        }
    }

    if (MODE == 1) {
        stats_accum_w<COUT, SPLIT, NW>(acc, valid, gw0, ls, stat_out);
        if (valid) {
#pragma unroll
            for (int j = 0; j < CT; ++j) out[(size_t)i * COUT + q * CT + j] = acc[j];
        }
    } else {   // MODE == 2: masked max-pool epilogue, wave-reduced
#pragma unroll
        for (int bb = 0; bb < B; ++bb) {
            float vv[CT];
#pragma unroll
            for (int j = 0; j < CT; ++j) vv[j] = (valid && b == bb) ? acc[j] : -INFINITY;
#pragma unroll
            for (int off = 1; off < 64; off <<= 1) {
#pragma unroll
                for (int j = 0; j < CT; ++j) vv[j] = fmaxf(vv[j], __shfl_xor(vv[j], off, 64));
            }
            if (lane == 0) {
#pragma unroll
                for (int j = 0; j < CT; ++j) atomicMax(&sm[bb * COUT + q * CT + j], encf(vv[j]));
            }
        }
        __syncthreads();
        if (tid < B * COUT) { unsigned e = sm[tid]; if (e) atomicMax(&pooled[tid], e); }
    }
}

// ---------------- DUAL stride-2 conv, wave-q, SGPR weights, branch-free --------
template <int SPLIT, int TB>
__global__ __launch_bounds__(TB, 2) void k_conv_s2_dual(const float* __restrict__ xs,
                                                     const unsigned long long* __restrict__ stat_in,
                                                     const float* __restrict__ gamma,
                                                     const float* __restrict__ beta,
                                                     const int* __restrict__ cnt_bn,
                                                     const int* __restrict__ map0,
                                                     const int* __restrict__ list1,
                                                     const int* __restrict__ cnt1,
                                                     const float* __restrict__ w1,
                                                     const float* __restrict__ w3,
                                                     float* __restrict__ out1,
                                                     float* __restrict__ out3,
                                                     unsigned long long* __restrict__ stat_out) {
    constexpr int CIN = C0, COUT = C1, CT = COUT / SPLIT;
    constexpr int NW = TB / 64;
    constexpr int NV4 = CIN / 4;
    __shared__ float ls[NW * 2 * CT];
    __shared__ float s_sc[CIN], s_sh[CIN];
    const int tid  = threadIdx.x;
    const int lane = tid & 63;
    const int gw0  = blockIdx.x * NW;
    const int n_act = cnt1[0];
    bn_prologue<CIN>(stat_in, gamma, beta, cnt_bn, s_sc, s_sh);
    __syncthreads();

    int gw = __builtin_amdgcn_readfirstlane(gw0 + (tid >> 6));
    int q  = gw % SPLIT;
    int c  = gw / SPLIT;
    int i  = c * 64 + lane;
    bool valid = i < n_act;

    float scr[CIN], shr[CIN];
#pragma unroll
    for (int ci = 0; ci < CIN; ++ci) { scr[ci] = s_sc[ci]; shr[ci] = s_sh[ci]; }

    float acc1[CT], acc3[CT];
#pragma unroll
    for (int j = 0; j < CT; ++j) { acc1[j] = 0.f; acc3[j] = 0.f; }

    if (c * 64 < n_act) {
        int ii = valid ? i : (n_act - 1);
        int v = list1[ii];
        int z = v % S1; int t2 = v / S1;
        int y = t2 % S1; t2 /= S1;
        int x = t2 % S1; int b = t2 / S1;
        int mm[27];
#pragma unroll
        for (int kx = 0; kx < 3; ++kx)
#pragma unroll
            for (int ky = 0; ky < 3; ++ky)
#pragma unroll
                for (int kz = 0; kz < 3; ++kz)
                    mm[(kx * 3 + ky) * 3 + kz] =
                        map0[((b * S + 2 * x + kx) * S + 2 * y + ky) * S + 2 * z + kz];

        auto rowp = [&](int m) {
            return reinterpret_cast<const float4*>(&xs[(size_t)(m > 0 ? m - 1 : 0) * CIN]);
        };
        float4 cr[NV4];
        {
            const float4* r = rowp(mm[0]);
#pragma unroll
            for (int u = 0; u < NV4; ++u) cr[u] = r[u];
        }
        const float* wq1 = w1 + q * CT;
        const float* wq3 = w3 + q * CT;
        for (int tap = 0; tap < 27; ++tap) {
            float4 nr[NV4];
            {
                const float4* r = rowp(mm[tap < 26 ? tap + 1 : 26]);
#pragma unroll
                for (int u = 0; u < NV4; ++u) nr[u] = r[u];
            }
            int m = mm[tap];
            const float* wt1 = wq1 + (size_t)tap * CIN * COUT;
            const float* wt3 = wq3 + (size_t)tap * CIN * COUT;
            float rv[CIN];
#pragma unroll
            for (int u = 0; u < NV4; ++u) {
                rv[4 * u] = cr[u].x; rv[4 * u + 1] = cr[u].y;
                rv[4 * u + 2] = cr[u].z; rv[4 * u + 3] = cr[u].w;
            }
#pragma unroll
            for (int ci = 0; ci < CIN; ++ci) {
                float g = fmaxf(fmaf(rv[ci], scr[ci], shr[ci]), 0.f);
                g = (m > 0) ? g : 0.f;
#pragma unroll
                for (int j = 0; j < CT; ++j) {
                    acc1[j] = fmaf(g, wt1[ci * COUT + j], acc1[j]);
                    acc3[j] = fmaf(g, wt3[ci * COUT + j], acc3[j]);
                }
            }
#pragma unroll
            for (int u = 0; u < NV4; ++u) cr[u] = nr[u];
        }
    }
    stats_accum_w<COUT, SPLIT, NW>(acc1, valid, gw0, ls, stat_out);
    if (valid) {
#pragma unroll
        for (int j = 0; j < CT; ++j) {
            out1[(size_t)i * COUT + q * CT + j] = acc1[j];
            out3[(size_t)i * COUT + q * CT + j] = acc3[j];
        }
    }
}

// ---------------- downsampled map + list (L1), block-aggregated append ----------------
__global__ __launch_bounds__(256) void k_map1(const int* __restrict__ map0, int* __restrict__ map1,
                                              int* __restrict__ list1, int* __restrict__ cnt1) {
    int v = blockIdx.x * 256 + threadIdx.x;
    bool valid = v < B * S13;
    bool act = false;
    if (valid) {
        int z = v % S1; int t = v / S1;
        int y = t % S1; t /= S1;
        int x = t % S1; int b = t / S1;
#pragma unroll
        for (int kx = 0; kx < 3; ++kx)
#pragma unroll
            for (int ky = 0; ky < 3; ++ky)
#pragma unroll
                for (int kz = 0; kz < 3; ++kz) {
                    int n = ((b * S + 2 * x + kx) * S + 2 * y + ky) * S + 2 * z + kz;
                    act = act || (map0[n] != 0);
                }
    }
    __shared__ int s_w[4];
    unsigned long long bm = __ballot(act);
    int lane = threadIdx.x & 63, wv = threadIdx.x >> 6;
    int cw = __popcll(bm);
    if (lane == 0) s_w[wv] = cw;
    __syncthreads();
    if (threadIdx.x == 0) {
        int tot = s_w[0] + s_w[1] + s_w[2] + s_w[3];
        int base = tot ? atomicAdd(cnt1, tot) : 0;
        int a = base;
        for (int k = 0; k < 4; ++k) { int c = s_w[k]; s_w[k] = a; a += c; }
    }
    __syncthreads();
    if (valid) {
        if (act) {
            int pos = s_w[wv] + __popcll(bm & ((1ull << lane) - 1ull));
            list1[pos] = v;
            map1[v] = pos + 1;
        } else {
            map1[v] = 0;
        }
    }
}

// ---------------- head: 2-layer MLP on pooled features ----------------
__global__ __launch_bounds__(64) void k_head(const unsigned* __restrict__ pooled,
                                             const float* __restrict__ l1w, const float* __restrict__ l1b,
                                             const float* __restrict__ l2w, const float* __restrict__ l2b,
                                             float* __restrict__ outp) {
    int t = threadIdx.x;               // 64 threads: b = t>>5, j = t&31
    int b = t >> 5, j = t & 31;
    float h = l1b[j];
#pragma unroll
    for (int c = 0; c < C1; ++c) {
        unsigned e = pooled[b * C1 + c];
        float p = (e == 0u) ? 0.f : decf(e);
        p = isfinite(p) ? p : 0.f;
        h = fmaf(l1w[j * C1 + c], p, h);
    }
    float val = l2w[j] * h;
#pragma unroll
    for (int off = 16; off > 0; off >>= 1) val += __shfl_down(val, off, 32);
    if (j == 0) outp[b] = val + l2b[0];
}

extern "C" void kernel_launch(void* const* d_in, const int* in_sizes, int n_in,
                              void* d_out, int out_size, void* d_ws, size_t ws_size,
                              hipStream_t stream) {
    const int*   coords = (const int*)  d_in[0];
    const float* feats  = (const float*)d_in[1];
    const float* w0     = (const float*)d_in[2];
    const float* g0     = (const float*)d_in[3];
    const float* b0     = (const float*)d_in[4];
    const float* ba0_g1 = (const float*)d_in[5];
    const float* ba0_b1 = (const float*)d_in[6];
    const float* ba0_w1 = (const float*)d_in[7];
    const float* ba0_g2 = (const float*)d_in[8];
    const float* ba0_b2 = (const float*)d_in[9];
    const float* ba0_w2 = (const float*)d_in[10];
    const float* ba1_g1 = (const float*)d_in[11];
    const float* ba1_b1 = (const float*)d_in[12];
    const float* ba1_w1 = (const float*)d_in[13];
    const float* ba1_g2 = (const float*)d_in[14];
    const float* ba1_b2 = (const float*)d_in[15];
    const float* ba1_w2 = (const float*)d_in[16];
    const float* bo0_g1 = (const float*)d_in[17];
    const float* bo0_b1 = (const float*)d_in[18];
    const float* bo0_w1 = (const float*)d_in[19];
    const float* bo0_g2 = (const float*)d_in[20];
    const float* bo0_b2 = (const float*)d_in[21];
    const float* bo0_w2 = (const float*)d_in[22];
    const float* bo1_g1 = (const float*)d_in[23];
    const float* bo1_b1 = (const float*)d_in[24];
    const float* bo1_w1 = (const float*)d_in[25];
    const float* bo1_g2 = (const float*)d_in[26];
    const float* bo1_b2 = (const float*)d_in[27];
    const float* bo1_w2 = (const float*)d_in[28];
    const float* dn_g1  = (const float*)d_in[29];
    const float* dn_b1  = (const float*)d_in[30];
    const float* dn_w1  = (const float*)d_in[31];
    const float* dn_g2  = (const float*)d_in[32];
    const float* dn_b2  = (const float*)d_in[33];
    const float* dn_w2  = (const float*)d_in[34];
    const float* dn_w3  = (const float*)d_in[35];
    const float* l1_w   = (const float*)d_in[36];
    const float* l1_b   = (const float*)d_in[37];
    const float* l2_w   = (const float*)d_in[38];
    const float* l2_b   = (const float*)d_in[39];

    char* p = (char*)d_ws;
    auto take = [&](size_t elems) -> float* {
        float* r = (float*)p;
        p += ((elems * 4 + 255) / 256) * 256;
        return r;
    };
    float* grid    = take((size_t)B * S3);
    int*   map0    = (int*)take((size_t)B * S3);
    float* x0      = take((size_t)NPTS * C0);
    float* t0      = take((size_t)NPTS * C0);
    int*   map1    = (int*)take((size_t)B * S13);
    float* t1      = take((size_t)B * S13 * C1);
    float* r1      = take((size_t)B * S13 * C1);
    float* x1      = take((size_t)B * S13 * C1);
    // zero-init region: stats (11 groups x 32 slots x 16 u64) + pooled + cnt
    unsigned long long* stats = (unsigned long long*)take(11 * 32 * STP * 2);
    unsigned* pooled = (unsigned*)take(B * C1);
    int*   cnt     = (int*)take(16);
    char* zero_end = p;
    int*   list0   = (int*)take(NPTS);
    int*   list1   = (int*)take((size_t)B * S13);
    int* cnt0 = cnt;
    int* cnt1 = cnt + 1;
    auto G = [&](int g) { return stats + (size_t)g * 32 * STP; };

    hipMemsetAsync(grid, 0, (size_t)((char*)x0 - (char*)grid), stream);
    hipMemsetAsync(stats, 0, (size_t)(zero_end - (char*)stats), stream);

    constexpr int TBW = 512;                                 // L1 conv block (8 waves)
    constexpr int SPL = 2;                                   // L1 wave-q split
    const int NB_C0 = (NPTS + 255) / 256;                    // 157
    const int NB_L0 = (NPTS * 4 + 255) / 256;                // 625 (lane-q SPLIT=4)
    const int NB_M1 = (B * S13 + 255) / 256;                 // 812
    const int CHUNKS = (B * S13 + 63) / 64;                  // 3245 (64 voxels/wave)
    const int NB_W  = (CHUNKS * SPL + (TBW / 64) - 1) / (TBW / 64);   // 812 blocks

    k_scatter<<<NB_C0, 256, 0, stream>>>(coords, feats, grid, map0, list0, cnt0);
    k_conv0s<<<NB_C0, 256, 0, stream>>>(grid, list0, cnt0, w0, x0, G(0));
    k_bn0<<<NB_C0, 256, 0, stream>>>(x0, cnt0, G(0), g0, b0, G(1));

    // ---- basic block ba0 (L0) ----
    k_conv_f<C0, C0, 4, S, 1, 256><<<NB_L0, 256, 0, stream>>>(x0, G(1), ba0_g1, ba0_b1, cnt0,
                                                              map0, list0, cnt0, ba0_w1, nullptr, t0, G(2), nullptr);
    k_conv_f<C0, C0, 4, S, 1, 256><<<NB_L0, 256, 0, stream>>>(t0, G(2), ba0_g2, ba0_b2, cnt0,
                                                              map0, list0, cnt0, ba0_w2, x0, x0, G(3), nullptr);

    // ---- basic block ba1 (L0) ----
    k_conv_f<C0, C0, 4, S, 1, 256><<<NB_L0, 256, 0, stream>>>(x0, G(3), ba1_g1, ba1_b1, cnt0,
                                                              map0, list0, cnt0, ba1_w1, nullptr, t0, G(4), nullptr);
    k_conv_f<C0, C0, 4, S, 1, 256><<<NB_L0, 256, 0, stream>>>(t0, G(4), ba1_g2, ba1_b2, cnt0,
                                                              map0, list0, cnt0, ba1_w2, x0, x0, G(5), nullptr);

    // ---- downsample: one gather, both stride-2 convs ----
    k_map1<<<NB_M1, 256, 0, stream>>>(map0, map1, list1, cnt1);
    k_conv_s2_dual<SPL, TBW><<<NB_W, TBW, 0, stream>>>(x0, G(5), dn_g1, dn_b1, cnt0,
                                                       map0, list1, cnt1, dn_w1, dn_w3, t1, r1, G(6));
    k_conv_w<C1, C1, SPL, 1, TBW><<<NB_W, TBW, 0, stream>>>(t1, G(6), dn_g2, dn_b2, cnt1,
                                                            map1, list1, cnt1, dn_w2, r1, x1, G(7), nullptr);

    // ---- basic block bo0 (L1) ----
    k_conv_w<C1, C1, SPL, 1, TBW><<<NB_W, TBW, 0, stream>>>(x1, G(7), bo0_g1, bo0_b1, cnt1,
                                                            map1, list1, cnt1, bo0_w1, nullptr, t1, G(8), nullptr);
    k_conv_w<C1, C1, SPL, 1, TBW><<<NB_W, TBW, 0, stream>>>(t1, G(8), bo0_g2, bo0_b2, cnt1,
                                                            map1, list1, cnt1, bo0_w2, x1, x1, G(9), nullptr);

    // ---- basic block bo1 (L1), final conv fused with max-pool ----
    k_conv_w<C1, C1, SPL, 1, TBW><<<NB_W, TBW, 0, stream>>>(x1, G(9), bo1_g1, bo1_b1, cnt1,
                                                            map1, list1, cnt1, bo1_w1, nullptr, t1, G(10), nullptr);
    k_conv_w<C1, C1, SPL, 2, TBW><<<NB_W, TBW, 0, stream>>>(t1, G(10), bo1_g2, bo1_b2, cnt1,
                                                            map1, list1, cnt1, bo1_w2, x1, nullptr, nullptr, pooled);

    // ---- head ----
    k_head<<<1, 64, 0, stream>>>(pooled, l1_w, l1_b, l2_w, l2_b, (float*)d_out);
}